// Round 1
// baseline (1793.119 us; speedup 1.0000x reference)
//
#include <hip/hip_runtime.h>
#include <hip/hip_bf16.h>

// ---------------- bf16 bit helpers (bf16 stored as raw ushort bits) ----------------
__device__ __forceinline__ float bfbits2f(unsigned short u) {
  return __uint_as_float(((unsigned int)u) << 16);
}
__device__ __forceinline__ unsigned short f2bfbits(float f) {
  unsigned int x = __float_as_uint(f);
  unsigned int r = (x + 0x7FFFu + ((x >> 16) & 1u)) >> 16;
  return (unsigned short)r;
}

typedef short bf16x8 __attribute__((ext_vector_type(8)));
typedef float f32x4 __attribute__((ext_vector_type(4)));

// ---------------- transpose + cast: fp32 [K][N] -> bf16 bits [N][K] ----------------
__global__ __launch_bounds__(256) void transpose_cast_k(const float* __restrict__ in,
                                                        unsigned short* __restrict__ out,
                                                        int K, int N) {
  __shared__ float tile[32][33];
  int n0 = blockIdx.x * 32, k0 = blockIdx.y * 32;
  int tx = threadIdx.x, ty = threadIdx.y;  // (32, 8)
#pragma unroll
  for (int j = 0; j < 32; j += 8)
    tile[ty + j][tx] = in[(size_t)(k0 + ty + j) * N + n0 + tx];
  __syncthreads();
#pragma unroll
  for (int j = 0; j < 32; j += 8)
    out[(size_t)(n0 + ty + j) * K + k0 + tx] = f2bfbits(tile[tx][ty + j]);
}

// ---------------- concat q/k/v biases into [3072] ----------------
__global__ void concat_bias_k(const float* __restrict__ bq, const float* __restrict__ bk,
                              const float* __restrict__ bv, float* __restrict__ out) {
  int i = blockIdx.x * 256 + threadIdx.x;
  if (i < 1024) {
    out[i] = bq[i];
    out[1024 + i] = bk[i];
    out[2048 + i] = bv[i];
  }
}

// ---------------- LayerNorm: fp32 [rows][1024] -> bf16 bits [rows][1024] ----------------
__global__ __launch_bounds__(256) void ln_k(const float* __restrict__ x,
                                            const float* __restrict__ g,
                                            const float* __restrict__ bb,
                                            unsigned short* __restrict__ out) {
  __shared__ float red[8];
  int row = blockIdx.x, tid = threadIdx.x;
  int lane = tid & 63, wv = tid >> 6;
  float4 v = reinterpret_cast<const float4*>(x + (size_t)row * 1024)[tid];
  float s = v.x + v.y + v.z + v.w;
#pragma unroll
  for (int off = 32; off >= 1; off >>= 1) s += __shfl_xor(s, off, 64);
  if (lane == 0) red[wv] = s;
  __syncthreads();
  float mu = (red[0] + red[1] + red[2] + red[3]) * (1.0f / 1024.0f);
  float a0 = v.x - mu, a1 = v.y - mu, a2 = v.z - mu, a3 = v.w - mu;
  float sq = a0 * a0 + a1 * a1 + a2 * a2 + a3 * a3;
#pragma unroll
  for (int off = 32; off >= 1; off >>= 1) sq += __shfl_xor(sq, off, 64);
  if (lane == 0) red[4 + wv] = sq;
  __syncthreads();
  float var = (red[4] + red[5] + red[6] + red[7]) * (1.0f / 1024.0f);
  float rstd = rsqrtf(var + 1e-5f);
  float4 gv = reinterpret_cast<const float4*>(g)[tid];
  float4 bv = reinterpret_cast<const float4*>(bb)[tid];
  ushort4 u;
  u.x = f2bfbits(a0 * rstd * gv.x + bv.x);
  u.y = f2bfbits(a1 * rstd * gv.y + bv.y);
  u.z = f2bfbits(a2 * rstd * gv.z + bv.z);
  u.w = f2bfbits(a3 * rstd * gv.w + bv.w);
  *reinterpret_cast<ushort4*>(out + (size_t)row * 1024 + tid * 4) = u;
}

// ---------------- bf16 MFMA GEMM:  C[M][N] = A[M][K] (bf16) @ BT[N][K]^T (bf16) + bias ----------------
// MODE 0: out bf16 = acc + bias          (QKV)
// MODE 1: out fp32 = acc + bias + resid  (Wo, W2; in-place resid==out is safe)
// MODE 2: out bf16 = gelu(acc + bias)    (W1)
template <int MODE>
__global__ __launch_bounds__(256) void gemm_bt_k(const unsigned short* __restrict__ A,
                                                 const unsigned short* __restrict__ BT,
                                                 const float* __restrict__ bias,
                                                 const float* __restrict__ resid,
                                                 void* __restrict__ Cout,
                                                 int M, int N, int K) {
  __shared__ unsigned short As[128][72];
  __shared__ unsigned short Bs[128][72];
  int tid = threadIdx.x;
  int wid = tid >> 6, lane = tid & 63;
  int m0 = blockIdx.x * 128, n0 = blockIdx.y * 128;
  int wr = wid >> 1, wc = wid & 1;  // 2x2 waves, each 64x64 output

  f32x4 acc[4][4];
#pragma unroll
  for (int i = 0; i < 4; i++)
#pragma unroll
    for (int j = 0; j < 4; j++)
#pragma unroll
      for (int r = 0; r < 4; r++) acc[i][j][r] = 0.0f;

  for (int k0 = 0; k0 < K; k0 += 64) {
    // stage 128x64 A and BT tiles (16B per thread per iter)
#pragma unroll
    for (int i = 0; i < 4; i++) {
      int c = i * 256 + tid;      // 0..1023
      int r = c >> 3;             // row 0..127
      int cc = (c & 7) * 8;       // col in bf16 elems
      *reinterpret_cast<uint4*>(&As[r][cc]) =
          *reinterpret_cast<const uint4*>(&A[(size_t)(m0 + r) * K + k0 + cc]);
      *reinterpret_cast<uint4*>(&Bs[r][cc]) =
          *reinterpret_cast<const uint4*>(&BT[(size_t)(n0 + r) * K + k0 + cc]);
    }
    __syncthreads();
#pragma unroll
    for (int kk = 0; kk < 64; kk += 32) {
      bf16x8 af[4], bfr[4];
      int row = lane & 15;
      int ko = kk + (lane >> 4) * 8;
#pragma unroll
      for (int mt = 0; mt < 4; mt++)
        af[mt] = *reinterpret_cast<const bf16x8*>(&As[wr * 64 + mt * 16 + row][ko]);
#pragma unroll
      for (int nt = 0; nt < 4; nt++)
        bfr[nt] = *reinterpret_cast<const bf16x8*>(&Bs[wc * 64 + nt * 16 + row][ko]);
#pragma unroll
      for (int mt = 0; mt < 4; mt++)
#pragma unroll
        for (int nt = 0; nt < 4; nt++)
          acc[mt][nt] = __builtin_amdgcn_mfma_f32_16x16x32_bf16(af[mt], bfr[nt], acc[mt][nt], 0, 0, 0);
    }
    __syncthreads();
  }

  // epilogue: D[row=(lane>>4)*4+r][col=lane&15] per 16x16 frag
  int col_l = lane & 15, row_l = (lane >> 4) * 4;
#pragma unroll
  for (int mt = 0; mt < 4; mt++) {
#pragma unroll
    for (int nt = 0; nt < 4; nt++) {
#pragma unroll
      for (int r = 0; r < 4; r++) {
        int gr = m0 + wr * 64 + mt * 16 + row_l + r;
        int gc = n0 + wc * 64 + nt * 16 + col_l;
        float v = acc[mt][nt][r] + bias[gc];
        if constexpr (MODE == 1) {
          v += resid[(size_t)gr * N + gc];
          ((float*)Cout)[(size_t)gr * N + gc] = v;
        } else if constexpr (MODE == 2) {
          v = 0.5f * v * (1.0f + erff(v * 0.70710678118654752f));
          ((unsigned short*)Cout)[(size_t)gr * N + gc] = f2bfbits(v);
        } else {
          ((unsigned short*)Cout)[(size_t)gr * N + gc] = f2bfbits(v);
        }
      }
    }
  }
}

// ---------------- causal attention ----------------
// qkv: bf16 bits [B*L][3072] (q | k | v, each col = h*64+d). out: bf16 bits [B*L][1024].
// One block: 16 queries of one (b,h). Online softmax over K/V tiles of 64.
__global__ __launch_bounds__(256) void attn_k(const unsigned short* __restrict__ qkv,
                                              unsigned short* __restrict__ out) {
  __shared__ float Qs[16][68];
  __shared__ float Ks[64][68];
  __shared__ float Vs[64][68];
  __shared__ float Sl[16][65];
  __shared__ float m_sh[16], l_sh[16], c_sh[16];

  int tid = threadIdx.x;
  int qt = blockIdx.x;  // 0..127
  int h = blockIdx.y;   // 0..15
  int b = blockIdx.z;   // 0..1
  int q0 = qt * 16;
  const int L = 2048, RS = 3072;

  // load Q (scaled by 1/sqrt(64))
  {
    int q = tid >> 4;
    int d0 = (tid & 15) * 4;
    const unsigned short* src = qkv + ((size_t)(b * L + q0 + q)) * RS + h * 64 + d0;
    ushort4 u = *reinterpret_cast<const ushort4*>(src);
    const float sc = 0.125f;
    Qs[q][d0 + 0] = bfbits2f(u.x) * sc;
    Qs[q][d0 + 1] = bfbits2f(u.y) * sc;
    Qs[q][d0 + 2] = bfbits2f(u.z) * sc;
    Qs[q][d0 + 3] = bfbits2f(u.w) * sc;
  }
  if (tid < 16) {
    m_sh[tid] = -1e30f;
    l_sh[tid] = 0.0f;
  }
  float o0 = 0.f, o1 = 0.f, o2 = 0.f, o3 = 0.f;
  int qg = q0 + (tid & 15);
  int ntiles = (q0 + 15) / 64 + 1;
  __syncthreads();

  for (int tt = 0; tt < ntiles; tt++) {
    int kb = tt * 64;
    // stage K/V tile (64 rows x 64 dims), bf16 -> fp32 LDS
#pragma unroll
    for (int i = 0; i < 4; i++) {
      int c = i * 256 + tid;  // 0..1023
      int r = c >> 4;
      int d0 = (c & 15) * 4;
      const unsigned short* kp = qkv + ((size_t)(b * L + kb + r)) * RS + 1024 + h * 64 + d0;
      ushort4 ku = *reinterpret_cast<const ushort4*>(kp);
      ushort4 vu = *reinterpret_cast<const ushort4*>(kp + 1024);
      Ks[r][d0 + 0] = bfbits2f(ku.x);
      Ks[r][d0 + 1] = bfbits2f(ku.y);
      Ks[r][d0 + 2] = bfbits2f(ku.z);
      Ks[r][d0 + 3] = bfbits2f(ku.w);
      Vs[r][d0 + 0] = bfbits2f(vu.x);
      Vs[r][d0 + 1] = bfbits2f(vu.y);
      Vs[r][d0 + 2] = bfbits2f(vu.z);
      Vs[r][d0 + 3] = bfbits2f(vu.w);
    }
    __syncthreads();
    // scores: thread -> (q = tid&15, 4 k's)
    {
      int q = tid & 15;
#pragma unroll
      for (int j = 0; j < 4; j++) {
        int k = (tid >> 4) + j * 16;
        float s = 0.f;
#pragma unroll
        for (int d = 0; d < 64; d++) s += Qs[q][d] * Ks[k][d];
        if (kb + k > qg) s = -1e30f;
        Sl[q][k] = s;
      }
    }
    __syncthreads();
    // online softmax: wave w owns rows 4w..4w+3
    {
      int wv = tid >> 6, lane = tid & 63;
      for (int rr = 0; rr < 4; rr++) {
        int r = wv * 4 + rr;
        float mold = m_sh[r];
        float s = Sl[r][lane];
        float rm = s;
#pragma unroll
        for (int off = 32; off >= 1; off >>= 1) rm = fmaxf(rm, __shfl_xor(rm, off, 64));
        float mnew = fmaxf(mold, rm);
        float p = __expf(s - mnew);
        Sl[r][lane] = p;
        float ps = p;
#pragma unroll
        for (int off = 32; off >= 1; off >>= 1) ps += __shfl_xor(ps, off, 64);
        if (lane == 0) {
          c_sh[r] = __expf(mold - mnew);
          l_sh[r] = l_sh[r] * c_sh[r] + ps;
          m_sh[r] = mnew;
        }
      }
    }
    __syncthreads();
    // PV: thread -> (q = tid&15, 4 dims d0..d0+3)
    {
      int q = tid & 15;
      int d0 = (tid >> 4) * 4;
      float corr = c_sh[q];
      o0 *= corr; o1 *= corr; o2 *= corr; o3 *= corr;
#pragma unroll 8
      for (int k = 0; k < 64; k++) {
        float p = Sl[q][k];
        float4 v = *reinterpret_cast<const float4*>(&Vs[k][d0]);
        o0 += p * v.x; o1 += p * v.y; o2 += p * v.z; o3 += p * v.w;
      }
    }
    __syncthreads();
  }
  // normalize + store
  {
    int q = tid & 15;
    int d0 = (tid >> 4) * 4;
    float linv = 1.0f / l_sh[q];
    ushort4 u;
    u.x = f2bfbits(o0 * linv);
    u.y = f2bfbits(o1 * linv);
    u.z = f2bfbits(o2 * linv);
    u.w = f2bfbits(o3 * linv);
    *reinterpret_cast<ushort4*>(out + ((size_t)(b * L + q0 + q)) * 1024 + h * 64 + d0) = u;
  }
}

// ---------------- launch ----------------
extern "C" void kernel_launch(void* const* d_in, const int* in_sizes, int n_in,
                              void* d_out, int out_size, void* d_ws, size_t ws_size,
                              hipStream_t stream) {
  const float* x = (const float*)d_in[0];
  const float* Wq = (const float*)d_in[2];
  const float* bq = (const float*)d_in[3];
  const float* Wk = (const float*)d_in[4];
  const float* bk = (const float*)d_in[5];
  const float* Wv = (const float*)d_in[6];
  const float* bv = (const float*)d_in[7];
  const float* Wo = (const float*)d_in[8];
  const float* bo = (const float*)d_in[9];
  const float* g1 = (const float*)d_in[10];
  const float* b1 = (const float*)d_in[11];
  const float* g2 = (const float*)d_in[12];
  const float* b2 = (const float*)d_in[13];
  const float* W1 = (const float*)d_in[14];
  const float* bf1 = (const float*)d_in[15];
  const float* W2 = (const float*)d_in[16];
  const float* bf2 = (const float*)d_in[17];
  float* out = (float*)d_out;

  const int M = 4096;  // B*L
  char* ws = (char*)d_ws;
  size_t off = 0;
  auto alloc = [&](size_t bytes) -> void* {
    void* p = ws + off;
    off += (bytes + 255) & ~(size_t)255;
    return p;
  };
  unsigned short* WqkvT = (unsigned short*)alloc((size_t)3072 * 1024 * 2);
  unsigned short* WoT = (unsigned short*)alloc((size_t)1024 * 1024 * 2);
  unsigned short* W1T = (unsigned short*)alloc((size_t)4096 * 1024 * 2);
  unsigned short* W2T = (unsigned short*)alloc((size_t)1024 * 4096 * 2);
  float* bqkv = (float*)alloc(3072 * 4);
  unsigned short* actA = (unsigned short*)alloc((size_t)M * 1024 * 2);  // nx / attn_out / nx2
  unsigned short* actB = (unsigned short*)alloc((size_t)M * 4096 * 2);  // qkv / h

  dim3 tb(32, 8);
  transpose_cast_k<<<dim3(32, 32), tb, 0, stream>>>(Wq, WqkvT, 1024, 1024);
  transpose_cast_k<<<dim3(32, 32), tb, 0, stream>>>(Wk, WqkvT + (size_t)1024 * 1024, 1024, 1024);
  transpose_cast_k<<<dim3(32, 32), tb, 0, stream>>>(Wv, WqkvT + (size_t)2048 * 1024, 1024, 1024);
  transpose_cast_k<<<dim3(32, 32), tb, 0, stream>>>(Wo, WoT, 1024, 1024);
  transpose_cast_k<<<dim3(128, 32), tb, 0, stream>>>(W1, W1T, 1024, 4096);
  transpose_cast_k<<<dim3(32, 128), tb, 0, stream>>>(W2, W2T, 4096, 1024);
  concat_bias_k<<<dim3(4), dim3(256), 0, stream>>>(bq, bk, bv, bqkv);

  // nx = LN1(x)
  ln_k<<<dim3(M), dim3(256), 0, stream>>>(x, g1, b1, actA);
  // qkv = nx @ [Wq|Wk|Wv] + b
  gemm_bt_k<0><<<dim3(M / 128, 3072 / 128), dim3(256), 0, stream>>>(actA, WqkvT, bqkv, nullptr, actB, M, 3072, 1024);
  // attn_out
  attn_k<<<dim3(128, 16, 2), dim3(256), 0, stream>>>(actB, actA);
  // x2 = x + attn_out @ Wo + bo   (fp32, into d_out)
  gemm_bt_k<1><<<dim3(M / 128, 1024 / 128), dim3(256), 0, stream>>>(actA, WoT, bo, x, out, M, 1024, 1024);
  // nx2 = LN2(x2)
  ln_k<<<dim3(M), dim3(256), 0, stream>>>(out, g2, b2, actA);
  // h = gelu(nx2 @ W1 + bf1)
  gemm_bt_k<2><<<dim3(M / 128, 4096 / 128), dim3(256), 0, stream>>>(actA, W1T, bf1, nullptr, actB, M, 4096, 1024);
  // out = x2 + h @ W2 + bf2  (in-place residual)
  gemm_bt_k<1><<<dim3(M / 128, 1024 / 128), dim3(256), 0, stream>>>(actB, W2T, bf2, out, out, M, 1024, 4096);
}

// Round 2
// 533.234 us; speedup vs baseline: 3.3627x; 3.3627x over previous
//
#include <hip/hip_runtime.h>
#include <hip/hip_bf16.h>

// ---------------- bf16 bit helpers (bf16 stored as raw ushort bits) ----------------
__device__ __forceinline__ float bfbits2f(unsigned short u) {
  return __uint_as_float(((unsigned int)u) << 16);
}
__device__ __forceinline__ unsigned short f2bfbits(float f) {
  unsigned int x = __float_as_uint(f);
  unsigned int r = (x + 0x7FFFu + ((x >> 16) & 1u)) >> 16;
  return (unsigned short)r;
}

typedef short bf16x8 __attribute__((ext_vector_type(8)));
typedef float f32x4 __attribute__((ext_vector_type(4)));

// async global->LDS, 16B per lane; LDS dest must be wave-uniform base (HW adds lane*16)
__device__ __forceinline__ void gload_lds16(const unsigned short* g, unsigned short* l) {
  __builtin_amdgcn_global_load_lds((const __attribute__((address_space(1))) unsigned int*)g,
                                   (__attribute__((address_space(3))) unsigned int*)l, 16, 0, 0);
}

// ---------------- transpose + cast: fp32 [K][N] -> bf16 bits [N][K] ----------------
__global__ __launch_bounds__(256) void transpose_cast_k(const float* __restrict__ in,
                                                        unsigned short* __restrict__ out,
                                                        int K, int N) {
  __shared__ float tile[32][33];
  int n0 = blockIdx.x * 32, k0 = blockIdx.y * 32;
  int tx = threadIdx.x, ty = threadIdx.y;  // (32, 8)
#pragma unroll
  for (int j = 0; j < 32; j += 8)
    tile[ty + j][tx] = in[(size_t)(k0 + ty + j) * N + n0 + tx];
  __syncthreads();
#pragma unroll
  for (int j = 0; j < 32; j += 8)
    out[(size_t)(n0 + ty + j) * K + k0 + tx] = f2bfbits(tile[tx][ty + j]);
}

// ---------------- concat q/k/v biases into [3072] ----------------
__global__ void concat_bias_k(const float* __restrict__ bq, const float* __restrict__ bk,
                              const float* __restrict__ bv, float* __restrict__ out) {
  int i = blockIdx.x * 256 + threadIdx.x;
  if (i < 1024) {
    out[i] = bq[i];
    out[1024 + i] = bk[i];
    out[2048 + i] = bv[i];
  }
}

// ---------------- LayerNorm: fp32 [rows][1024] -> bf16 bits [rows][1024] ----------------
__global__ __launch_bounds__(256) void ln_k(const float* __restrict__ x,
                                            const float* __restrict__ g,
                                            const float* __restrict__ bb,
                                            unsigned short* __restrict__ out) {
  __shared__ float red[8];
  int row = blockIdx.x, tid = threadIdx.x;
  int lane = tid & 63, wv = tid >> 6;
  float4 v = reinterpret_cast<const float4*>(x + (size_t)row * 1024)[tid];
  float s = v.x + v.y + v.z + v.w;
#pragma unroll
  for (int off = 32; off >= 1; off >>= 1) s += __shfl_xor(s, off, 64);
  if (lane == 0) red[wv] = s;
  __syncthreads();
  float mu = (red[0] + red[1] + red[2] + red[3]) * (1.0f / 1024.0f);
  float a0 = v.x - mu, a1 = v.y - mu, a2 = v.z - mu, a3 = v.w - mu;
  float sq = a0 * a0 + a1 * a1 + a2 * a2 + a3 * a3;
#pragma unroll
  for (int off = 32; off >= 1; off >>= 1) sq += __shfl_xor(sq, off, 64);
  if (lane == 0) red[4 + wv] = sq;
  __syncthreads();
  float var = (red[4] + red[5] + red[6] + red[7]) * (1.0f / 1024.0f);
  float rstd = rsqrtf(var + 1e-5f);
  float4 gv = reinterpret_cast<const float4*>(g)[tid];
  float4 bv = reinterpret_cast<const float4*>(bb)[tid];
  ushort4 u;
  u.x = f2bfbits(a0 * rstd * gv.x + bv.x);
  u.y = f2bfbits(a1 * rstd * gv.y + bv.y);
  u.z = f2bfbits(a2 * rstd * gv.z + bv.z);
  u.w = f2bfbits(a3 * rstd * gv.w + bv.w);
  *reinterpret_cast<ushort4*>(out + (size_t)row * 1024 + tid * 4) = u;
}

// ---------------- bf16 MFMA GEMM (m97 structure): C = A @ BT^T + bias ----------------
// linear LDS [128][64], global_load_lds 16B staging, 2 barriers / K-step.
// MODE 0: out bf16 = acc + bias          (QKV)
// MODE 1: out fp32 = acc + bias + resid  (Wo, W2; in-place resid==out is safe)
// MODE 2: out bf16 = gelu(acc + bias)    (W1)
template <int MODE>
__global__ __launch_bounds__(256) void gemm_bt_k(const unsigned short* __restrict__ A,
                                                 const unsigned short* __restrict__ BT,
                                                 const float* __restrict__ bias,
                                                 const float* __restrict__ resid,
                                                 void* __restrict__ Cout,
                                                 int M, int N, int K) {
  __shared__ unsigned short As[128 * 64];
  __shared__ unsigned short Bs[128 * 64];
  int tid = threadIdx.x;
  int wid = tid >> 6, lane = tid & 63;
  int m0 = blockIdx.x * 128, n0 = blockIdx.y * 128;
  int wr = wid >> 1, wc = wid & 1;  // 2x2 waves, each 64x64 output
  int cl = lane & 15, g = lane >> 4;

  f32x4 acc[4][4];
#pragma unroll
  for (int i = 0; i < 4; i++)
#pragma unroll
    for (int j = 0; j < 4; j++) acc[i][j] = {0.f, 0.f, 0.f, 0.f};

  for (int k0 = 0; k0 < K; k0 += 64) {
#pragma unroll
    for (int i = 0; i < 4; ++i) {
      int c = i * 256 + tid;   // 16B-chunk index; lane-linear within wave
      int r = c >> 3;
      int cc = (c & 7) * 8;
      gload_lds16(&A[(size_t)(m0 + r) * K + k0 + cc], &As[(i * 256 + wid * 64) * 8]);
      gload_lds16(&BT[(size_t)(n0 + r) * K + k0 + cc], &Bs[(i * 256 + wid * 64) * 8]);
    }
    __syncthreads();  // drains vmcnt -> LDS tiles ready
#pragma unroll
    for (int kk = 0; kk < 64; kk += 32) {
      bf16x8 af[4], bfr[4];
#pragma unroll
      for (int mt = 0; mt < 4; mt++)
        af[mt] = *reinterpret_cast<const bf16x8*>(&As[(wr * 64 + mt * 16 + cl) * 64 + kk + g * 8]);
#pragma unroll
      for (int nt = 0; nt < 4; nt++)
        bfr[nt] = *reinterpret_cast<const bf16x8*>(&Bs[(wc * 64 + nt * 16 + cl) * 64 + kk + g * 8]);
#pragma unroll
      for (int mt = 0; mt < 4; mt++)
#pragma unroll
        for (int nt = 0; nt < 4; nt++)
          acc[mt][nt] = __builtin_amdgcn_mfma_f32_16x16x32_bf16(af[mt], bfr[nt], acc[mt][nt], 0, 0, 0);
    }
    __syncthreads();
  }

  // epilogue: D[row=(lane>>4)*4+r][col=lane&15] per 16x16 frag
#pragma unroll
  for (int mt = 0; mt < 4; mt++) {
#pragma unroll
    for (int nt = 0; nt < 4; nt++) {
#pragma unroll
      for (int r = 0; r < 4; r++) {
        int gr = m0 + wr * 64 + mt * 16 + g * 4 + r;
        int gc = n0 + wc * 64 + nt * 16 + cl;
        float v = acc[mt][nt][r] + bias[gc];
        if constexpr (MODE == 1) {
          v += resid[(size_t)gr * N + gc];
          ((float*)Cout)[(size_t)gr * N + gc] = v;
        } else if constexpr (MODE == 2) {
          v = 0.5f * v * (1.0f + erff(v * 0.70710678118654752f));
          ((unsigned short*)Cout)[(size_t)gr * N + gc] = f2bfbits(v);
        } else {
          ((unsigned short*)Cout)[(size_t)gr * N + gc] = f2bfbits(v);
        }
      }
    }
  }
}

// ---------------- MFMA flash attention (causal) ----------------
// qkv bf16 [B*L][3072] (q|k|v, col = h*64+d) -> out bf16 [B*L][1024].
// Block: (q-tile of 64) x head x batch; 4 waves, each 16 q-rows. KV tiles of 64.
// LDS tiles XOR-swizzled: element (row,d) chunk c=d/8 stored at chunk c^(row&7).
__global__ __launch_bounds__(256) void attn_k(const unsigned short* __restrict__ qkv,
                                              unsigned short* __restrict__ out) {
  __shared__ unsigned short Ks[64 * 64];     // [k-row][d], swizzled
  __shared__ unsigned short Vt[64 * 64];     // [d-row][k], swizzled (V transposed)
  __shared__ unsigned short Ps[4][16 * 64];  // per-wave P [q][k], swizzled

  const int L = 2048, RS = 3072;
  int tid = threadIdx.x;
  int wid = tid >> 6, lane = tid & 63;
  int qt = (int)gridDim.x - 1 - (int)blockIdx.x;  // heavy tiles dispatch first
  int h = blockIdx.y, b = blockIdx.z;
  int q0 = qt * 64;
  int qw = q0 + wid * 16;
  int g = lane >> 4;
  int cl = lane & 15;

  // Q fragments hoisted to registers: a_frag row=cl, d=g*8+e (two K=32 halves)
  const unsigned short* qbase = qkv + (size_t)(b * L + qw + cl) * RS + h * 64 + g * 8;
  bf16x8 qf0 = *reinterpret_cast<const bf16x8*>(qbase);
  bf16x8 qf1 = *reinterpret_cast<const bf16x8*>(qbase + 32);

  float m_r[4], l_r[4];
  f32x4 o_acc[4];
#pragma unroll
  for (int r = 0; r < 4; ++r) { m_r[r] = -1e30f; l_r[r] = 0.f; }
#pragma unroll
  for (int d = 0; d < 4; ++d) o_acc[d] = {0.f, 0.f, 0.f, 0.f};

  const unsigned short* kvbase = qkv + (size_t)(b * L) * RS + 1024 + h * 64;
  int ntiles = qt + 1;

  for (int tt = 0; tt < ntiles; ++tt) {
    int kb = tt * 64;
    // ---- stage K via global_load_lds, source pre-swizzled (linear dest + swizzled read) ----
#pragma unroll
    for (int it = 0; it < 2; ++it) {
      int idx = it * 256 + tid;  // 16B chunk: row r = idx>>3, chunk ch = idx&7
      int r = idx >> 3, ch = idx & 7;
      gload_lds16(kvbase + (size_t)(kb + r) * RS + (ch ^ (r & 7)) * 8,
                  &Ks[(it * 256 + wid * 64) * 8]);
    }
    // ---- stage V transposed (reg-staged scatter), swizzled writes ----
    {
      int kcol = tid & 63;
      int d0 = wid * 16;
      const unsigned short* vsrc = kvbase + (size_t)(kb + kcol) * RS + 1024 + d0;
      bf16x8 v0 = *reinterpret_cast<const bf16x8*>(vsrc);
      bf16x8 v1 = *reinterpret_cast<const bf16x8*>(vsrc + 8);
#pragma unroll
      for (int j = 0; j < 8; ++j) {
        int d = d0 + j;
        Vt[d * 64 + 8 * ((kcol >> 3) ^ (d & 7)) + (kcol & 7)] = (unsigned short)v0[j];
        int d2 = d0 + 8 + j;
        Vt[d2 * 64 + 8 * ((kcol >> 3) ^ (d2 & 7)) + (kcol & 7)] = (unsigned short)v1[j];
      }
    }
    __syncthreads();  // drains vmcnt(0)+lgkmcnt(0): K and Vt ready

    // ---- S = (Q K^T) * scale ----
    f32x4 sacc[4];
#pragma unroll
    for (int kblk = 0; kblk < 4; ++kblk) sacc[kblk] = {0.f, 0.f, 0.f, 0.f};
#pragma unroll
    for (int kblk = 0; kblk < 4; ++kblk) {
      int kcol = kblk * 16 + cl;
      bf16x8 kf0 = *reinterpret_cast<const bf16x8*>(&Ks[kcol * 64 + 8 * (g ^ (kcol & 7))]);
      bf16x8 kf1 = *reinterpret_cast<const bf16x8*>(&Ks[kcol * 64 + 8 * ((g + 4) ^ (kcol & 7))]);
      sacc[kblk] = __builtin_amdgcn_mfma_f32_16x16x32_bf16(qf0, kf0, sacc[kblk], 0, 0, 0);
      sacc[kblk] = __builtin_amdgcn_mfma_f32_16x16x32_bf16(qf1, kf1, sacc[kblk], 0, 0, 0);
    }

    // ---- online softmax; rows owned per-lane: q_local = g*4 + r ----
    bool lastTile = (tt == ntiles - 1);
    float rowmax[4];
#pragma unroll
    for (int r = 0; r < 4; ++r) {
      float mx = -1e30f;
#pragma unroll
      for (int kblk = 0; kblk < 4; ++kblk) {
        float s = sacc[kblk][r] * 0.125f;
        if (lastTile && (kblk * 16 + cl > wid * 16 + g * 4 + r)) s = -1e30f;  // causal
        sacc[kblk][r] = s;
        mx = fmaxf(mx, s);
      }
      rowmax[r] = mx;
    }
#pragma unroll
    for (int off = 1; off <= 8; off <<= 1)
#pragma unroll
      for (int r = 0; r < 4; ++r) rowmax[r] = fmaxf(rowmax[r], __shfl_xor(rowmax[r], off, 64));
#pragma unroll
    for (int r = 0; r < 4; ++r) {
      float mnew = fmaxf(m_r[r], rowmax[r]);
      float corr = __expf(m_r[r] - mnew);
      m_r[r] = mnew;
      int q_l = g * 4 + r;
      float rs = 0.f;
#pragma unroll
      for (int kblk = 0; kblk < 4; ++kblk) {
        float p = __expf(sacc[kblk][r] - mnew);
        rs += p;
        int k_l = kblk * 16 + cl;
        Ps[wid][q_l * 64 + 8 * ((k_l >> 3) ^ (q_l & 7)) + (k_l & 7)] = f2bfbits(p);
      }
#pragma unroll
      for (int off = 1; off <= 8; off <<= 1) rs += __shfl_xor(rs, off, 64);
      l_r[r] = l_r[r] * corr + rs;
#pragma unroll
      for (int dblk = 0; dblk < 4; ++dblk) o_acc[dblk][r] *= corr;
    }
    // wave-private Ps write->read ordering (DS in-order + explicit drain; rule #18 fence)
    asm volatile("s_waitcnt lgkmcnt(0)" ::: "memory");
    __builtin_amdgcn_sched_barrier(0);

    // ---- O += P @ V ----
    bf16x8 pa0 = *reinterpret_cast<const bf16x8*>(&Ps[wid][cl * 64 + 8 * (g ^ (cl & 7))]);
    bf16x8 pa1 = *reinterpret_cast<const bf16x8*>(&Ps[wid][cl * 64 + 8 * ((g + 4) ^ (cl & 7))]);
#pragma unroll
    for (int dblk = 0; dblk < 4; ++dblk) {
      int d = dblk * 16 + cl;
      bf16x8 vb0 = *reinterpret_cast<const bf16x8*>(&Vt[d * 64 + 8 * (g ^ (d & 7))]);
      bf16x8 vb1 = *reinterpret_cast<const bf16x8*>(&Vt[d * 64 + 8 * ((g + 4) ^ (d & 7))]);
      o_acc[dblk] = __builtin_amdgcn_mfma_f32_16x16x32_bf16(pa0, vb0, o_acc[dblk], 0, 0, 0);
      o_acc[dblk] = __builtin_amdgcn_mfma_f32_16x16x32_bf16(pa1, vb1, o_acc[dblk], 0, 0, 0);
    }
    __syncthreads();  // protect Ks/Vt before next tile's staging
  }

  // ---- normalize + store ----
#pragma unroll
  for (int r = 0; r < 4; ++r) {
    float linv = 1.0f / l_r[r];
    int orow = qw + g * 4 + r;
    unsigned short* obase = out + (size_t)(b * L + orow) * 1024 + h * 64;
#pragma unroll
    for (int dblk = 0; dblk < 4; ++dblk)
      obase[dblk * 16 + cl] = f2bfbits(o_acc[dblk][r] * linv);
  }
}

// ---------------- launch ----------------
extern "C" void kernel_launch(void* const* d_in, const int* in_sizes, int n_in,
                              void* d_out, int out_size, void* d_ws, size_t ws_size,
                              hipStream_t stream) {
  const float* x = (const float*)d_in[0];
  const float* Wq = (const float*)d_in[2];
  const float* bq = (const float*)d_in[3];
  const float* Wk = (const float*)d_in[4];
  const float* bk = (const float*)d_in[5];
  const float* Wv = (const float*)d_in[6];
  const float* bv = (const float*)d_in[7];
  const float* Wo = (const float*)d_in[8];
  const float* bo = (const float*)d_in[9];
  const float* g1 = (const float*)d_in[10];
  const float* b1 = (const float*)d_in[11];
  const float* g2 = (const float*)d_in[12];
  const float* b2 = (const float*)d_in[13];
  const float* W1 = (const float*)d_in[14];
  const float* bf1 = (const float*)d_in[15];
  const float* W2 = (const float*)d_in[16];
  const float* bf2 = (const float*)d_in[17];
  float* out = (float*)d_out;

  const int M = 4096;  // B*L
  char* ws = (char*)d_ws;
  size_t off = 0;
  auto alloc = [&](size_t bytes) -> void* {
    void* p = ws + off;
    off += (bytes + 255) & ~(size_t)255;
    return p;
  };
  unsigned short* WqkvT = (unsigned short*)alloc((size_t)3072 * 1024 * 2);
  unsigned short* WoT = (unsigned short*)alloc((size_t)1024 * 1024 * 2);
  unsigned short* W1T = (unsigned short*)alloc((size_t)4096 * 1024 * 2);
  unsigned short* W2T = (unsigned short*)alloc((size_t)1024 * 4096 * 2);
  float* bqkv = (float*)alloc(3072 * 4);
  unsigned short* actA = (unsigned short*)alloc((size_t)M * 1024 * 2);  // nx / attn_out / nx2
  unsigned short* actB = (unsigned short*)alloc((size_t)M * 4096 * 2);  // qkv / h

  dim3 tb(32, 8);
  transpose_cast_k<<<dim3(32, 32), tb, 0, stream>>>(Wq, WqkvT, 1024, 1024);
  transpose_cast_k<<<dim3(32, 32), tb, 0, stream>>>(Wk, WqkvT + (size_t)1024 * 1024, 1024, 1024);
  transpose_cast_k<<<dim3(32, 32), tb, 0, stream>>>(Wv, WqkvT + (size_t)2048 * 1024, 1024, 1024);
  transpose_cast_k<<<dim3(32, 32), tb, 0, stream>>>(Wo, WoT, 1024, 1024);
  transpose_cast_k<<<dim3(128, 32), tb, 0, stream>>>(W1, W1T, 1024, 4096);
  transpose_cast_k<<<dim3(32, 128), tb, 0, stream>>>(W2, W2T, 4096, 1024);
  concat_bias_k<<<dim3(4), dim3(256), 0, stream>>>(bq, bk, bv, bqkv);

  // nx = LN1(x)
  ln_k<<<dim3(M), dim3(256), 0, stream>>>(x, g1, b1, actA);
  // qkv = nx @ [Wq|Wk|Wv] + b
  gemm_bt_k<0><<<dim3(M / 128, 3072 / 128), dim3(256), 0, stream>>>(actA, WqkvT, bqkv, nullptr, actB, M, 3072, 1024);
  // attn_out
  attn_k<<<dim3(32, 16, 2), dim3(256), 0, stream>>>(actB, actA);
  // x2 = x + attn_out @ Wo + bo   (fp32, into d_out)
  gemm_bt_k<1><<<dim3(M / 128, 1024 / 128), dim3(256), 0, stream>>>(actA, WoT, bo, x, out, M, 1024, 1024);
  // nx2 = LN2(x2)
  ln_k<<<dim3(M), dim3(256), 0, stream>>>(out, g2, b2, actA);
  // h = gelu(nx2 @ W1 + bf1)
  gemm_bt_k<2><<<dim3(M / 128, 4096 / 128), dim3(256), 0, stream>>>(actA, W1T, bf1, nullptr, actB, M, 4096, 1024);
  // out = x2 + h @ W2 + bf2  (in-place residual)
  gemm_bt_k<1><<<dim3(M / 128, 1024 / 128), dim3(256), 0, stream>>>(actB, W2T, bf2, out, out, M, 1024, 4096);
}

// Round 3
// 531.456 us; speedup vs baseline: 3.3740x; 1.0033x over previous
//
#include <hip/hip_runtime.h>
#include <hip/hip_bf16.h>

// ---------------- bf16 bit helpers (bf16 stored as raw ushort bits) ----------------
__device__ __forceinline__ float bfbits2f(unsigned short u) {
  return __uint_as_float(((unsigned int)u) << 16);
}
__device__ __forceinline__ unsigned short f2bfbits(float f) {
  unsigned int x = __float_as_uint(f);
  unsigned int r = (x + 0x7FFFu + ((x >> 16) & 1u)) >> 16;
  return (unsigned short)r;
}

typedef short bf16x8 __attribute__((ext_vector_type(8)));
typedef float f32x4 __attribute__((ext_vector_type(4)));

// async global->LDS, 16B per lane; LDS dest must be wave-uniform base (HW adds lane*16)
__device__ __forceinline__ void gload_lds16(const unsigned short* g, unsigned short* l) {
  __builtin_amdgcn_global_load_lds((const __attribute__((address_space(1))) unsigned int*)g,
                                   (__attribute__((address_space(3))) unsigned int*)l, 16, 0, 0);
}

// ---------------- transpose + cast: fp32 [K][N] -> bf16 bits [N][K] ----------------
__global__ __launch_bounds__(256) void transpose_cast_k(const float* __restrict__ in,
                                                        unsigned short* __restrict__ out,
                                                        int K, int N) {
  __shared__ float tile[32][33];
  int n0 = blockIdx.x * 32, k0 = blockIdx.y * 32;
  int tx = threadIdx.x, ty = threadIdx.y;  // (32, 8)
#pragma unroll
  for (int j = 0; j < 32; j += 8)
    tile[ty + j][tx] = in[(size_t)(k0 + ty + j) * N + n0 + tx];
  __syncthreads();
#pragma unroll
  for (int j = 0; j < 32; j += 8)
    out[(size_t)(n0 + ty + j) * K + k0 + tx] = f2bfbits(tile[tx][ty + j]);
}

// four square 1024x1024 transposes in one launch (z = which)
__global__ __launch_bounds__(256) void transpose_cast4_k(const float* __restrict__ w0,
                                                         const float* __restrict__ w1,
                                                         const float* __restrict__ w2,
                                                         const float* __restrict__ w3,
                                                         unsigned short* __restrict__ o012,
                                                         unsigned short* __restrict__ o3) {
  __shared__ float tile[32][33];
  int z = blockIdx.z;
  const float* in = (z == 0) ? w0 : (z == 1) ? w1 : (z == 2) ? w2 : w3;
  unsigned short* out = (z < 3) ? (o012 + (size_t)z * 1024 * 1024) : o3;
  int n0 = blockIdx.x * 32, k0 = blockIdx.y * 32;
  int tx = threadIdx.x, ty = threadIdx.y;
#pragma unroll
  for (int j = 0; j < 32; j += 8)
    tile[ty + j][tx] = in[(size_t)(k0 + ty + j) * 1024 + n0 + tx];
  __syncthreads();
#pragma unroll
  for (int j = 0; j < 32; j += 8)
    out[(size_t)(n0 + ty + j) * 1024 + k0 + tx] = f2bfbits(tile[tx][ty + j]);
}

// ---------------- concat q/k/v biases into [3072] ----------------
__global__ void concat_bias_k(const float* __restrict__ bq, const float* __restrict__ bk,
                              const float* __restrict__ bv, float* __restrict__ out) {
  int i = blockIdx.x * 256 + threadIdx.x;
  if (i < 1024) {
    out[i] = bq[i];
    out[1024 + i] = bk[i];
    out[2048 + i] = bv[i];
  }
}

// ---------------- LayerNorm: fp32 [rows][1024] -> bf16 bits [rows][1024] ----------------
__global__ __launch_bounds__(256) void ln_k(const float* __restrict__ x,
                                            const float* __restrict__ g,
                                            const float* __restrict__ bb,
                                            unsigned short* __restrict__ out) {
  __shared__ float red[8];
  int row = blockIdx.x, tid = threadIdx.x;
  int lane = tid & 63, wv = tid >> 6;
  float4 v = reinterpret_cast<const float4*>(x + (size_t)row * 1024)[tid];
  float s = v.x + v.y + v.z + v.w;
#pragma unroll
  for (int off = 32; off >= 1; off >>= 1) s += __shfl_xor(s, off, 64);
  if (lane == 0) red[wv] = s;
  __syncthreads();
  float mu = (red[0] + red[1] + red[2] + red[3]) * (1.0f / 1024.0f);
  float a0 = v.x - mu, a1 = v.y - mu, a2 = v.z - mu, a3 = v.w - mu;
  float sq = a0 * a0 + a1 * a1 + a2 * a2 + a3 * a3;
#pragma unroll
  for (int off = 32; off >= 1; off >>= 1) sq += __shfl_xor(sq, off, 64);
  if (lane == 0) red[4 + wv] = sq;
  __syncthreads();
  float var = (red[4] + red[5] + red[6] + red[7]) * (1.0f / 1024.0f);
  float rstd = rsqrtf(var + 1e-5f);
  float4 gv = reinterpret_cast<const float4*>(g)[tid];
  float4 bv = reinterpret_cast<const float4*>(bb)[tid];
  ushort4 u;
  u.x = f2bfbits(a0 * rstd * gv.x + bv.x);
  u.y = f2bfbits(a1 * rstd * gv.y + bv.y);
  u.z = f2bfbits(a2 * rstd * gv.z + bv.z);
  u.w = f2bfbits(a3 * rstd * gv.w + bv.w);
  *reinterpret_cast<ushort4*>(out + (size_t)row * 1024 + tid * 4) = u;
}

// ---------------- bf16 MFMA GEMM (m97 structure): C = A @ BT^T + bias ----------------
template <int MODE>
__global__ __launch_bounds__(256) void gemm_bt_k(const unsigned short* __restrict__ A,
                                                 const unsigned short* __restrict__ BT,
                                                 const float* __restrict__ bias,
                                                 const float* __restrict__ resid,
                                                 void* __restrict__ Cout,
                                                 int M, int N, int K) {
  __shared__ unsigned short As[128 * 64];
  __shared__ unsigned short Bs[128 * 64];
  int tid = threadIdx.x;
  int wid = tid >> 6, lane = tid & 63;
  int m0 = blockIdx.x * 128, n0 = blockIdx.y * 128;
  int wr = wid >> 1, wc = wid & 1;  // 2x2 waves, each 64x64 output
  int cl = lane & 15, g = lane >> 4;

  f32x4 acc[4][4];
#pragma unroll
  for (int i = 0; i < 4; i++)
#pragma unroll
    for (int j = 0; j < 4; j++) acc[i][j] = {0.f, 0.f, 0.f, 0.f};

  for (int k0 = 0; k0 < K; k0 += 64) {
#pragma unroll
    for (int i = 0; i < 4; ++i) {
      int c = i * 256 + tid;
      int r = c >> 3;
      int cc = (c & 7) * 8;
      gload_lds16(&A[(size_t)(m0 + r) * K + k0 + cc], &As[(i * 256 + wid * 64) * 8]);
      gload_lds16(&BT[(size_t)(n0 + r) * K + k0 + cc], &Bs[(i * 256 + wid * 64) * 8]);
    }
    __syncthreads();
#pragma unroll
    for (int kk = 0; kk < 64; kk += 32) {
      bf16x8 af[4], bfr[4];
#pragma unroll
      for (int mt = 0; mt < 4; mt++)
        af[mt] = *reinterpret_cast<const bf16x8*>(&As[(wr * 64 + mt * 16 + cl) * 64 + kk + g * 8]);
#pragma unroll
      for (int nt = 0; nt < 4; nt++)
        bfr[nt] = *reinterpret_cast<const bf16x8*>(&Bs[(wc * 64 + nt * 16 + cl) * 64 + kk + g * 8]);
#pragma unroll
      for (int mt = 0; mt < 4; mt++)
#pragma unroll
        for (int nt = 0; nt < 4; nt++)
          acc[mt][nt] = __builtin_amdgcn_mfma_f32_16x16x32_bf16(af[mt], bfr[nt], acc[mt][nt], 0, 0, 0);
    }
    __syncthreads();
  }

#pragma unroll
  for (int mt = 0; mt < 4; mt++) {
#pragma unroll
    for (int nt = 0; nt < 4; nt++) {
#pragma unroll
      for (int r = 0; r < 4; r++) {
        int gr = m0 + wr * 64 + mt * 16 + g * 4 + r;
        int gc = n0 + wc * 64 + nt * 16 + cl;
        float v = acc[mt][nt][r] + bias[gc];
        if constexpr (MODE == 1) {
          v += resid[(size_t)gr * N + gc];
          ((float*)Cout)[(size_t)gr * N + gc] = v;
        } else if constexpr (MODE == 2) {
          v = 0.5f * v * (1.0f + erff(v * 0.70710678118654752f));
          ((unsigned short*)Cout)[(size_t)gr * N + gc] = f2bfbits(v);
        } else {
          ((unsigned short*)Cout)[(size_t)gr * N + gc] = f2bfbits(v);
        }
      }
    }
  }
}

// ---------------- MFMA flash attention v3 (causal, pipelined) ----------------
// 8 waves, QBLK=128 (wave = 16 q rows), KV tiles of 64.
// K double-buffered via global_load_lds (source pre-swizzled); V prefetched to regs,
// scattered transposed+swizzled to LDS; raw barriers with explicit waitcnt so the
// prefetch stays in flight across the mid-tile barrier.
__global__ __launch_bounds__(512) void attn_k(const unsigned short* __restrict__ qkv,
                                              unsigned short* __restrict__ out) {
  __shared__ unsigned short Ks[2][64 * 64];  // [k-row][d], swizzled chunks
  __shared__ unsigned short Vt[64 * 64];     // [d-row][k], swizzled (V transposed)
  __shared__ unsigned short Ps[8][16 * 64];  // per-wave P [q][k], swizzled

  const int L = 2048, RS = 3072;
  const float SCALE = 0.125f * 1.44269504f;  // 1/sqrt(64) * log2(e)
  int tid = threadIdx.x;
  int wid = tid >> 6, lane = tid & 63;
  int qt = (int)gridDim.x - 1 - (int)blockIdx.x;  // heavy tiles dispatch first
  int h = blockIdx.y, b = blockIdx.z;
  int q0 = qt * 128;
  int qw = q0 + wid * 16;
  int g = lane >> 4;
  int cl = lane & 15;

  const unsigned short* kbase = qkv + (size_t)(b * L) * RS + 1024 + h * 64;
  const unsigned short* vbase = kbase + 1024;

  // Q fragments hoisted: a_frag row=cl, d=g*8+e (two K=32 halves)
  const unsigned short* qbase = qkv + (size_t)(b * L + qw + cl) * RS + h * 64 + g * 8;
  bf16x8 qf0 = *reinterpret_cast<const bf16x8*>(qbase);
  bf16x8 qf1 = *reinterpret_cast<const bf16x8*>(qbase + 32);

  // K staging address (per thread covers one 16B chunk of the 64x64 tile)
  int kr = tid >> 3, kch = tid & 7;
  size_t ksrc_off = (size_t)kr * RS + ((kch ^ (kr & 7)) * 8);
  // V staging: thread loads V[vk][vd0..vd0+7], scatters to Vt columns (swizzled)
  int vk = tid & 63, vd0 = (tid >> 6) * 8;
  int vaddr[8];
#pragma unroll
  for (int j = 0; j < 8; ++j) {
    int d = vd0 + j;
    vaddr[j] = d * 64 + 8 * ((vk >> 3) ^ (d & 7)) + (vk & 7);
  }

  float m_r[4], l_r[4];
  f32x4 o_acc[4];
#pragma unroll
  for (int r = 0; r < 4; ++r) { m_r[r] = -1e30f; l_r[r] = 0.f; }
#pragma unroll
  for (int d = 0; d < 4; ++d) o_acc[d] = {0.f, 0.f, 0.f, 0.f};

  int nt = 2 * qt + 2;

  // prologue: issue tile 0 (K -> LDS buf0, V -> regs)
  gload_lds16(kbase + ksrc_off, &Ks[0][wid * 512]);
  bf16x8 vreg = *reinterpret_cast<const bf16x8*>(vbase + (size_t)vk * RS + vd0);

  int buf = 0;
  for (int tt = 0; tt < nt; ++tt) {
    int kb = tt * 64;
    // ---- tile-top: my K(t)/V(t) loads done, then align all waves ----
    asm volatile("s_waitcnt vmcnt(0)" ::: "memory");
    __builtin_amdgcn_s_barrier();
    __builtin_amdgcn_sched_barrier(0);

    // ---- scatter V(t) regs -> Vt (transposed, swizzled) ----
#pragma unroll
    for (int j = 0; j < 8; ++j) Vt[vaddr[j]] = (unsigned short)vreg[j];

    // ---- prefetch tile t+1 (stays in flight across the mid barrier) ----
    if (tt + 1 < nt) {
      int kb1 = (size_t)(tt + 1) * 64;
      gload_lds16(kbase + (size_t)kb1 * RS + ksrc_off, &Ks[buf ^ 1][wid * 512]);
      vreg = *reinterpret_cast<const bf16x8*>(vbase + (size_t)(kb1 + vk) * RS + vd0);
    }

    // ---- S = Q K^T (reads Ks[buf]) ----
    f32x4 sacc[4];
#pragma unroll
    for (int kblk = 0; kblk < 4; ++kblk) sacc[kblk] = {0.f, 0.f, 0.f, 0.f};
#pragma unroll
    for (int kblk = 0; kblk < 4; ++kblk) {
      int kcol = kblk * 16 + cl;
      bf16x8 kf0 = *reinterpret_cast<const bf16x8*>(&Ks[buf][kcol * 64 + 8 * (g ^ (kcol & 7))]);
      bf16x8 kf1 = *reinterpret_cast<const bf16x8*>(&Ks[buf][kcol * 64 + 8 * ((g + 4) ^ (kcol & 7))]);
      sacc[kblk] = __builtin_amdgcn_mfma_f32_16x16x32_bf16(qf0, kf0, sacc[kblk], 0, 0, 0);
      sacc[kblk] = __builtin_amdgcn_mfma_f32_16x16x32_bf16(qf1, kf1, sacc[kblk], 0, 0, 0);
    }

    // ---- online softmax (exp2 domain); lane owns rows q_l = g*4+r ----
    float rowmax[4];
    if (kb + 63 <= qw) {  // fully unmasked tile for this wave
#pragma unroll
      for (int r = 0; r < 4; ++r) {
        float mx = -1e30f;
#pragma unroll
        for (int kblk = 0; kblk < 4; ++kblk) {
          float s = sacc[kblk][r] * SCALE;
          sacc[kblk][r] = s;
          mx = fmaxf(mx, s);
        }
        rowmax[r] = mx;
      }
    } else {
#pragma unroll
      for (int r = 0; r < 4; ++r) {
        float mx = -1e30f;
        int qg = qw + g * 4 + r;
#pragma unroll
        for (int kblk = 0; kblk < 4; ++kblk) {
          float s = sacc[kblk][r] * SCALE;
          if (kb + kblk * 16 + cl > qg) s = -1e30f;  // causal
          sacc[kblk][r] = s;
          mx = fmaxf(mx, s);
        }
        rowmax[r] = mx;
      }
    }
#pragma unroll
    for (int off = 1; off <= 8; off <<= 1)
#pragma unroll
      for (int r = 0; r < 4; ++r) rowmax[r] = fmaxf(rowmax[r], __shfl_xor(rowmax[r], off, 64));
#pragma unroll
    for (int r = 0; r < 4; ++r) {
      float mnew = fmaxf(m_r[r], rowmax[r]);
      float corr = exp2f(m_r[r] - mnew);
      m_r[r] = mnew;
      int q_l = g * 4 + r;
      float rs = 0.f;
#pragma unroll
      for (int kblk = 0; kblk < 4; ++kblk) {
        float p = exp2f(sacc[kblk][r] - mnew);
        rs += p;
        int k_l = kblk * 16 + cl;
        Ps[wid][q_l * 64 + 8 * ((k_l >> 3) ^ (q_l & 7)) + (k_l & 7)] = f2bfbits(p);
      }
#pragma unroll
      for (int off = 1; off <= 8; off <<= 1) rs += __shfl_xor(rs, off, 64);
      l_r[r] = l_r[r] * corr + rs;
#pragma unroll
      for (int dblk = 0; dblk < 4; ++dblk) o_acc[dblk][r] *= corr;
    }

    // ---- mid barrier: Vt + Ps writes visible; prefetch (vmcnt) NOT drained ----
    asm volatile("s_waitcnt lgkmcnt(0)" ::: "memory");
    __builtin_amdgcn_s_barrier();
    __builtin_amdgcn_sched_barrier(0);

    // ---- O += P @ V ----
    bf16x8 pa0 = *reinterpret_cast<const bf16x8*>(&Ps[wid][cl * 64 + 8 * (g ^ (cl & 7))]);
    bf16x8 pa1 = *reinterpret_cast<const bf16x8*>(&Ps[wid][cl * 64 + 8 * ((g + 4) ^ (cl & 7))]);
#pragma unroll
    for (int dblk = 0; dblk < 4; ++dblk) {
      int d = dblk * 16 + cl;
      bf16x8 vb0 = *reinterpret_cast<const bf16x8*>(&Vt[d * 64 + 8 * (g ^ (d & 7))]);
      bf16x8 vb1 = *reinterpret_cast<const bf16x8*>(&Vt[d * 64 + 8 * ((g + 4) ^ (d & 7))]);
      o_acc[dblk] = __builtin_amdgcn_mfma_f32_16x16x32_bf16(pa0, vb0, o_acc[dblk], 0, 0, 0);
      o_acc[dblk] = __builtin_amdgcn_mfma_f32_16x16x32_bf16(pa1, vb1, o_acc[dblk], 0, 0, 0);
    }
    buf ^= 1;
  }

  // ---- normalize + store ----
#pragma unroll
  for (int r = 0; r < 4; ++r) {
    float linv = 1.0f / l_r[r];
    int orow = qw + g * 4 + r;
    unsigned short* obase = out + (size_t)(b * L + orow) * 1024 + h * 64;
#pragma unroll
    for (int dblk = 0; dblk < 4; ++dblk)
      obase[dblk * 16 + cl] = f2bfbits(o_acc[dblk][r] * linv);
  }
}

// ---------------- launch ----------------
extern "C" void kernel_launch(void* const* d_in, const int* in_sizes, int n_in,
                              void* d_out, int out_size, void* d_ws, size_t ws_size,
                              hipStream_t stream) {
  const float* x = (const float*)d_in[0];
  const float* Wq = (const float*)d_in[2];
  const float* bq = (const float*)d_in[3];
  const float* Wk = (const float*)d_in[4];
  const float* bk = (const float*)d_in[5];
  const float* Wv = (const float*)d_in[6];
  const float* bv = (const float*)d_in[7];
  const float* Wo = (const float*)d_in[8];
  const float* bo = (const float*)d_in[9];
  const float* g1 = (const float*)d_in[10];
  const float* b1 = (const float*)d_in[11];
  const float* g2 = (const float*)d_in[12];
  const float* b2 = (const float*)d_in[13];
  const float* W1 = (const float*)d_in[14];
  const float* bf1 = (const float*)d_in[15];
  const float* W2 = (const float*)d_in[16];
  const float* bf2 = (const float*)d_in[17];
  float* out = (float*)d_out;

  const int M = 4096;  // B*L
  char* ws = (char*)d_ws;
  size_t off = 0;
  auto alloc = [&](size_t bytes) -> void* {
    void* p = ws + off;
    off += (bytes + 255) & ~(size_t)255;
    return p;
  };
  unsigned short* WqkvT = (unsigned short*)alloc((size_t)3072 * 1024 * 2);
  unsigned short* WoT = (unsigned short*)alloc((size_t)1024 * 1024 * 2);
  unsigned short* W1T = (unsigned short*)alloc((size_t)4096 * 1024 * 2);
  unsigned short* W2T = (unsigned short*)alloc((size_t)1024 * 4096 * 2);
  float* bqkv = (float*)alloc(3072 * 4);
  unsigned short* actA = (unsigned short*)alloc((size_t)M * 1024 * 2);  // nx / attn_out / nx2
  unsigned short* actB = (unsigned short*)alloc((size_t)M * 4096 * 2);  // qkv / h

  dim3 tb(32, 8);
  transpose_cast4_k<<<dim3(32, 32, 4), tb, 0, stream>>>(Wq, Wk, Wv, Wo, WqkvT, WoT);
  transpose_cast_k<<<dim3(128, 32), tb, 0, stream>>>(W1, W1T, 1024, 4096);
  transpose_cast_k<<<dim3(32, 128), tb, 0, stream>>>(W2, W2T, 4096, 1024);
  concat_bias_k<<<dim3(4), dim3(256), 0, stream>>>(bq, bk, bv, bqkv);

  // nx = LN1(x)
  ln_k<<<dim3(M), dim3(256), 0, stream>>>(x, g1, b1, actA);
  // qkv = nx @ [Wq|Wk|Wv] + b
  gemm_bt_k<0><<<dim3(M / 128, 3072 / 128), dim3(256), 0, stream>>>(actA, WqkvT, bqkv, nullptr, actB, M, 3072, 1024);
  // attn_out
  attn_k<<<dim3(16, 16, 2), dim3(512), 0, stream>>>(actB, actA);
  // x2 = x + attn_out @ Wo + bo   (fp32, into d_out)
  gemm_bt_k<1><<<dim3(M / 128, 1024 / 128), dim3(256), 0, stream>>>(actA, WoT, bo, x, out, M, 1024, 1024);
  // nx2 = LN2(x2)
  ln_k<<<dim3(M), dim3(256), 0, stream>>>(out, g2, b2, actA);
  // h = gelu(nx2 @ W1 + bf1)
  gemm_bt_k<2><<<dim3(M / 128, 4096 / 128), dim3(256), 0, stream>>>(actA, W1T, bf1, nullptr, actB, M, 4096, 1024);
  // out = x2 + h @ W2 + bf2  (in-place residual)
  gemm_bt_k<1><<<dim3(M / 128, 1024 / 128), dim3(256), 0, stream>>>(actB, W2T, bf2, out, out, M, 1024, 4096);
}

// Round 4
// 469.092 us; speedup vs baseline: 3.8225x; 1.1329x over previous
//
#include <hip/hip_runtime.h>
#include <hip/hip_bf16.h>

// ---------------- bf16 bit helpers (bf16 stored as raw ushort bits) ----------------
__device__ __forceinline__ float bfbits2f(unsigned short u) {
  return __uint_as_float(((unsigned int)u) << 16);
}
__device__ __forceinline__ unsigned short f2bfbits(float f) {
  unsigned int x = __float_as_uint(f);
  unsigned int r = (x + 0x7FFFu + ((x >> 16) & 1u)) >> 16;
  return (unsigned short)r;
}

typedef short bf16x8 __attribute__((ext_vector_type(8)));
typedef float f32x4 __attribute__((ext_vector_type(4)));
typedef float f32x16 __attribute__((ext_vector_type(16)));
typedef int i32x4 __attribute__((ext_vector_type(4)));

// v_cvt_pk_bf16_f32: pack two f32 -> u32 of 2 bf16 (RNE)
__device__ __forceinline__ int cvtpk(float lo, float hi_) {
  int r;
  asm("v_cvt_pk_bf16_f32 %0, %1, %2" : "=v"(r) : "v"(lo), "v"(hi_));
  return r;
}
// v_permlane32_swap_b32: a.hi <-> b.lo  (in-place pair swap)
__device__ __forceinline__ void plswap(int& a, int& b) {
  asm("v_permlane32_swap_b32 %0, %1" : "+v"(a), "+v"(b));
}
__device__ __forceinline__ bf16x8 mk8(int a, int b, int c, int d) {
  i32x4 t = {a, b, c, d};
  return __builtin_bit_cast(bf16x8, t);
}

// async global->LDS, 16B per lane; LDS dest must be wave-uniform base (HW adds lane*16)
__device__ __forceinline__ void gload_lds16(const unsigned short* g, unsigned short* l) {
  __builtin_amdgcn_global_load_lds((const __attribute__((address_space(1))) unsigned int*)g,
                                   (__attribute__((address_space(3))) unsigned int*)l, 16, 0, 0);
}

// ---------------- transpose + cast: fp32 [K][N] -> bf16 bits [N][K] ----------------
__global__ __launch_bounds__(256) void transpose_cast_k(const float* __restrict__ in,
                                                        unsigned short* __restrict__ out,
                                                        int K, int N) {
  __shared__ float tile[32][33];
  int n0 = blockIdx.x * 32, k0 = blockIdx.y * 32;
  int tx = threadIdx.x, ty = threadIdx.y;  // (32, 8)
#pragma unroll
  for (int j = 0; j < 32; j += 8)
    tile[ty + j][tx] = in[(size_t)(k0 + ty + j) * N + n0 + tx];
  __syncthreads();
#pragma unroll
  for (int j = 0; j < 32; j += 8)
    out[(size_t)(n0 + ty + j) * K + k0 + tx] = f2bfbits(tile[tx][ty + j]);
}

// four square 1024x1024 transposes in one launch (z = which)
__global__ __launch_bounds__(256) void transpose_cast4_k(const float* __restrict__ w0,
                                                         const float* __restrict__ w1,
                                                         const float* __restrict__ w2,
                                                         const float* __restrict__ w3,
                                                         unsigned short* __restrict__ o012,
                                                         unsigned short* __restrict__ o3) {
  __shared__ float tile[32][33];
  int z = blockIdx.z;
  const float* in = (z == 0) ? w0 : (z == 1) ? w1 : (z == 2) ? w2 : w3;
  unsigned short* out = (z < 3) ? (o012 + (size_t)z * 1024 * 1024) : o3;
  int n0 = blockIdx.x * 32, k0 = blockIdx.y * 32;
  int tx = threadIdx.x, ty = threadIdx.y;
#pragma unroll
  for (int j = 0; j < 32; j += 8)
    tile[ty + j][tx] = in[(size_t)(k0 + ty + j) * 1024 + n0 + tx];
  __syncthreads();
#pragma unroll
  for (int j = 0; j < 32; j += 8)
    out[(size_t)(n0 + ty + j) * 1024 + k0 + tx] = f2bfbits(tile[tx][ty + j]);
}

// ---------------- concat q/k/v biases into [3072] ----------------
__global__ void concat_bias_k(const float* __restrict__ bq, const float* __restrict__ bk,
                              const float* __restrict__ bv, float* __restrict__ out) {
  int i = blockIdx.x * 256 + threadIdx.x;
  if (i < 1024) {
    out[i] = bq[i];
    out[1024 + i] = bk[i];
    out[2048 + i] = bv[i];
  }
}

// ---------------- LayerNorm: fp32 [rows][1024] -> bf16 bits [rows][1024] ----------------
__global__ __launch_bounds__(256) void ln_k(const float* __restrict__ x,
                                            const float* __restrict__ g,
                                            const float* __restrict__ bb,
                                            unsigned short* __restrict__ out) {
  __shared__ float red[8];
  int row = blockIdx.x, tid = threadIdx.x;
  int lane = tid & 63, wv = tid >> 6;
  float4 v = reinterpret_cast<const float4*>(x + (size_t)row * 1024)[tid];
  float s = v.x + v.y + v.z + v.w;
#pragma unroll
  for (int off = 32; off >= 1; off >>= 1) s += __shfl_xor(s, off, 64);
  if (lane == 0) red[wv] = s;
  __syncthreads();
  float mu = (red[0] + red[1] + red[2] + red[3]) * (1.0f / 1024.0f);
  float a0 = v.x - mu, a1 = v.y - mu, a2 = v.z - mu, a3 = v.w - mu;
  float sq = a0 * a0 + a1 * a1 + a2 * a2 + a3 * a3;
#pragma unroll
  for (int off = 32; off >= 1; off >>= 1) sq += __shfl_xor(sq, off, 64);
  if (lane == 0) red[4 + wv] = sq;
  __syncthreads();
  float var = (red[4] + red[5] + red[6] + red[7]) * (1.0f / 1024.0f);
  float rstd = rsqrtf(var + 1e-5f);
  float4 gv = reinterpret_cast<const float4*>(g)[tid];
  float4 bv = reinterpret_cast<const float4*>(bb)[tid];
  ushort4 u;
  u.x = f2bfbits(a0 * rstd * gv.x + bv.x);
  u.y = f2bfbits(a1 * rstd * gv.y + bv.y);
  u.z = f2bfbits(a2 * rstd * gv.z + bv.z);
  u.w = f2bfbits(a3 * rstd * gv.w + bv.w);
  *reinterpret_cast<ushort4*>(out + (size_t)row * 1024 + tid * 4) = u;
}

// ---------------- bf16 MFMA GEMM (m97 structure): C = A @ BT^T + bias ----------------
template <int MODE>
__global__ __launch_bounds__(256) void gemm_bt_k(const unsigned short* __restrict__ A,
                                                 const unsigned short* __restrict__ BT,
                                                 const float* __restrict__ bias,
                                                 const float* __restrict__ resid,
                                                 void* __restrict__ Cout,
                                                 int M, int N, int K) {
  __shared__ unsigned short As[128 * 64];
  __shared__ unsigned short Bs[128 * 64];
  int tid = threadIdx.x;
  int wid = tid >> 6, lane = tid & 63;
  int m0 = blockIdx.x * 128, n0 = blockIdx.y * 128;
  int wr = wid >> 1, wc = wid & 1;  // 2x2 waves, each 64x64 output
  int cl = lane & 15, g = lane >> 4;

  f32x4 acc[4][4];
#pragma unroll
  for (int i = 0; i < 4; i++)
#pragma unroll
    for (int j = 0; j < 4; j++) acc[i][j] = {0.f, 0.f, 0.f, 0.f};

  for (int k0 = 0; k0 < K; k0 += 64) {
#pragma unroll
    for (int i = 0; i < 4; ++i) {
      int c = i * 256 + tid;
      int r = c >> 3;
      int cc = (c & 7) * 8;
      gload_lds16(&A[(size_t)(m0 + r) * K + k0 + cc], &As[(i * 256 + wid * 64) * 8]);
      gload_lds16(&BT[(size_t)(n0 + r) * K + k0 + cc], &Bs[(i * 256 + wid * 64) * 8]);
    }
    __syncthreads();
#pragma unroll
    for (int kk = 0; kk < 64; kk += 32) {
      bf16x8 af[4], bfr[4];
#pragma unroll
      for (int mt = 0; mt < 4; mt++)
        af[mt] = *reinterpret_cast<const bf16x8*>(&As[(wr * 64 + mt * 16 + cl) * 64 + kk + g * 8]);
#pragma unroll
      for (int nt = 0; nt < 4; nt++)
        bfr[nt] = *reinterpret_cast<const bf16x8*>(&Bs[(wc * 64 + nt * 16 + cl) * 64 + kk + g * 8]);
#pragma unroll
      for (int mt = 0; mt < 4; mt++)
#pragma unroll
        for (int nt = 0; nt < 4; nt++)
          acc[mt][nt] = __builtin_amdgcn_mfma_f32_16x16x32_bf16(af[mt], bfr[nt], acc[mt][nt], 0, 0, 0);
    }
    __syncthreads();
  }

#pragma unroll
  for (int mt = 0; mt < 4; mt++) {
#pragma unroll
    for (int nt = 0; nt < 4; nt++) {
#pragma unroll
      for (int r = 0; r < 4; r++) {
        int gr = m0 + wr * 64 + mt * 16 + g * 4 + r;
        int gc = n0 + wc * 64 + nt * 16 + cl;
        float v = acc[mt][nt][r] + bias[gc];
        if constexpr (MODE == 1) {
          v += resid[(size_t)gr * N + gc];
          ((float*)Cout)[(size_t)gr * N + gc] = v;
        } else if constexpr (MODE == 2) {
          v = 0.5f * v * (1.0f + erff(v * 0.70710678118654752f));
          ((unsigned short*)Cout)[(size_t)gr * N + gc] = f2bfbits(v);
        } else {
          ((unsigned short*)Cout)[(size_t)gr * N + gc] = f2bfbits(v);
        }
      }
    }
  }
}

// ---------------- MFMA flash attention v4: swapped-operand 32x32, in-register softmax ----------------
// qkv bf16 [B*L][3072] (q|k|v, col=h*64+d) -> out bf16 [B*L][1024].
// Block: 256 thr = 4 waves; QBLK=128 (wave owns 32 q rows, q = lane&31). KV tiles of 64.
// S^T = mfma_32x32x16(K, Q): lane holds a q-row's 32 scores -> in-lane softmax,
// P packed via cvt_pk_bf16 + permlane32_swap (no LDS for P). O^T = mfma(V^T, P^T).
// K: global_load_lds double-buffered (pre-swizzled source); V: reg-prefetched, b32 scatter.
__global__ __launch_bounds__(256) void attn_k(const unsigned short* __restrict__ qkv,
                                              unsigned short* __restrict__ out) {
  __shared__ unsigned short Ks[2][64 * 64];  // [k-row][d], 16B-chunk c stored at c^(row&7)
  __shared__ unsigned short Vt[64 * 64];     // [d-row][k], same swizzle

  const int L = 2048, RS = 3072;
  const float SCALE = 0.125f * 1.44269504f;  // 1/sqrt(64) * log2(e)
  int tid = threadIdx.x;
  int wid = tid >> 6, lane = tid & 63;
  int qt = (int)gridDim.x - 1 - (int)blockIdx.x;  // heavy tiles dispatch first
  int h = blockIdx.y, b = blockIdx.z;
  int q0 = qt * 128;
  int qw = q0 + wid * 32;
  int ql = lane & 31;
  int hi = lane >> 5;
  int qg = qw + ql;

  const unsigned short* kbase = qkv + (size_t)(b * L) * RS + 1024 + h * 64;
  const unsigned short* vbase = kbase + 1024;

  // ---- Q fragments (B-frag: col=q=lane&31, k=d=hi*8+e), pre-scaled by SCALE ----
  bf16x8 qf[4];
  {
    const unsigned short* qp = qkv + (size_t)(b * L + qg) * RS + h * 64 + hi * 8;
#pragma unroll
    for (int s = 0; s < 4; ++s) {
      bf16x8 qr = *reinterpret_cast<const bf16x8*>(qp + s * 16);
      int w0 = cvtpk(bfbits2f((unsigned short)qr[0]) * SCALE, bfbits2f((unsigned short)qr[1]) * SCALE);
      int w1 = cvtpk(bfbits2f((unsigned short)qr[2]) * SCALE, bfbits2f((unsigned short)qr[3]) * SCALE);
      int w2 = cvtpk(bfbits2f((unsigned short)qr[4]) * SCALE, bfbits2f((unsigned short)qr[5]) * SCALE);
      int w3 = cvtpk(bfbits2f((unsigned short)qr[6]) * SCALE, bfbits2f((unsigned short)qr[7]) * SCALE);
      qf[s] = mk8(w0, w1, w2, w3);
    }
  }

  // ---- K staging: thread covers swizzled chunks tid and tid+256 ----
  int kr0 = tid >> 3, kc0 = tid & 7;
  size_t koff0 = (size_t)kr0 * RS + ((kc0 ^ (kr0 & 7)) * 8);  // +32*RS for second half
  // ---- V staging: thread loads rows vkp,vkp+1 (8 d each), writes 8 packed b32 ----
  int vkp = (tid & 31) * 2, vd0 = (tid >> 5) * 8;
  int vwaddr[8];
#pragma unroll
  for (int j = 0; j < 8; ++j) {
    int d = vd0 + j;
    vwaddr[j] = d * 64 + (((vkp >> 3) ^ (d & 7)) << 3) + (vkp & 7);
  }

  float m_r = -3.0e38f, l_r = 0.f;
  f32x16 oA, oB;
#pragma unroll
  for (int r = 0; r < 16; ++r) { oA[r] = 0.f; oB[r] = 0.f; }

  int nt = 2 * qt + 2;

  // prologue: issue tile 0
  gload_lds16(kbase + koff0, &Ks[0][(wid * 64) * 8]);
  gload_lds16(kbase + koff0 + (size_t)32 * RS, &Ks[0][(256 + wid * 64) * 8]);
  bf16x8 vr0, vr1;
  {
    const unsigned short* vp = vbase + (size_t)vkp * RS + vd0;
    vr0 = *reinterpret_cast<const bf16x8*>(vp);
    vr1 = *reinterpret_cast<const bf16x8*>(vp + RS);
  }

  int buf = 0;
  for (int tt = 0; tt < nt; ++tt) {
    int kb = tt * 64;
    // ---- tile-top: my K(t)/V(t) loads done; align waves ----
    asm volatile("s_waitcnt vmcnt(0)" ::: "memory");
    __builtin_amdgcn_s_barrier();
    __builtin_amdgcn_sched_barrier(0);

    // ---- scatter V(t) regs -> Vt (transposed, swizzled, b32-packed) ----
#pragma unroll
    for (int j = 0; j < 8; ++j) {
      unsigned int pk = (unsigned int)(unsigned short)vr0[j] |
                        ((unsigned int)(unsigned short)vr1[j] << 16);
      *reinterpret_cast<unsigned int*>(&Vt[vwaddr[j]]) = pk;
    }

    // ---- prefetch tile t+1 (stays in flight across the mid barrier) ----
    if (tt + 1 < nt) {
      size_t kb1r = (size_t)(tt + 1) * 64 * RS;
      gload_lds16(kbase + kb1r + koff0, &Ks[buf ^ 1][(wid * 64) * 8]);
      gload_lds16(kbase + kb1r + koff0 + (size_t)32 * RS, &Ks[buf ^ 1][(256 + wid * 64) * 8]);
      const unsigned short* vp = vbase + kb1r + (size_t)vkp * RS + vd0;
      vr0 = *reinterpret_cast<const bf16x8*>(vp);
      vr1 = *reinterpret_cast<const bf16x8*>(vp + RS);
    }

    // ---- S^T = mfma(K, Q): rows k = lane&31 (+32), cols q ----
    f32x16 s0, s1;
#pragma unroll
    for (int r = 0; r < 16; ++r) { s0[r] = 0.f; s1[r] = 0.f; }
#pragma unroll
    for (int s = 0; s < 4; ++s) {
      int ch = ((s * 2 + hi) ^ (ql & 7)) * 8;
      bf16x8 ka0 = *reinterpret_cast<const bf16x8*>(&Ks[buf][ql * 64 + ch]);
      bf16x8 ka1 = *reinterpret_cast<const bf16x8*>(&Ks[buf][(32 + ql) * 64 + ch]);
      s0 = __builtin_amdgcn_mfma_f32_32x32x16_bf16(ka0, qf[s], s0, 0, 0, 0);
      s1 = __builtin_amdgcn_mfma_f32_32x32x16_bf16(ka1, qf[s], s1, 0, 0, 0);
    }

    // ---- causal mask (k = kb + (r&3)+8*(r>>2)+4*hi [+32]) ----
    if (kb + 63 > qw) {
#pragma unroll
      for (int r = 0; r < 16; ++r) {
        int ko = kb + (r & 3) + 8 * (r >> 2) + 4 * hi;
        if (ko > qg) s0[r] = -3.0e38f;
        if (ko + 32 > qg) s1[r] = -3.0e38f;
      }
    }

    // ---- in-register online softmax (exp2 domain) ----
#define MX4(v, i) fmaxf(fmaxf(v[i], v[i + 1]), fmaxf(v[i + 2], v[i + 3]))
    float ma = fmaxf(fmaxf(MX4(s0, 0), MX4(s0, 4)), fmaxf(MX4(s0, 8), MX4(s0, 12)));
    float mb = fmaxf(fmaxf(MX4(s1, 0), MX4(s1, 4)), fmaxf(MX4(s1, 8), MX4(s1, 12)));
    float mx = fmaxf(ma, mb);
    mx = fmaxf(mx, __shfl_xor(mx, 32, 64));
    float mnew = fmaxf(m_r, mx);
    float corr = exp2f(m_r - mnew);
    m_r = mnew;
#pragma unroll
    for (int r = 0; r < 16; ++r) {
      s0[r] = exp2f(s0[r] - mnew);
      s1[r] = exp2f(s1[r] - mnew);
    }
#define SM4(v, i) ((v[i] + v[i + 1]) + (v[i + 2] + v[i + 3]))
    float rs = ((SM4(s0, 0) + SM4(s0, 4)) + (SM4(s0, 8) + SM4(s0, 12))) +
               ((SM4(s1, 0) + SM4(s1, 4)) + (SM4(s1, 8) + SM4(s1, 12)));
    rs += __shfl_xor(rs, 32, 64);
    l_r = l_r * corr + rs;
#pragma unroll
    for (int r = 0; r < 16; ++r) { oA[r] *= corr; oB[r] *= corr; }

    // ---- pack P -> bf16 frags in-register (cvt_pk + permlane32_swap) ----
    int c0 = cvtpk(s0[0], s0[1]), c1 = cvtpk(s0[2], s0[3]);
    int c2 = cvtpk(s0[4], s0[5]), c3 = cvtpk(s0[6], s0[7]);
    int c4 = cvtpk(s0[8], s0[9]), c5 = cvtpk(s0[10], s0[11]);
    int c6 = cvtpk(s0[12], s0[13]), c7 = cvtpk(s0[14], s0[15]);
    plswap(c0, c2); plswap(c1, c3); plswap(c4, c6); plswap(c5, c7);
    bf16x8 p00 = mk8(c0, c1, c2, c3);  // kt0, k 0..15
    bf16x8 p01 = mk8(c4, c5, c6, c7);  // kt0, k 16..31
    int d0 = cvtpk(s1[0], s1[1]), d1 = cvtpk(s1[2], s1[3]);
    int d2 = cvtpk(s1[4], s1[5]), d3 = cvtpk(s1[6], s1[7]);
    int d4 = cvtpk(s1[8], s1[9]), d5 = cvtpk(s1[10], s1[11]);
    int d6 = cvtpk(s1[12], s1[13]), d7 = cvtpk(s1[14], s1[15]);
    plswap(d0, d2); plswap(d1, d3); plswap(d4, d6); plswap(d5, d7);
    bf16x8 p10 = mk8(d0, d1, d2, d3);  // kt1, k 32..47
    bf16x8 p11 = mk8(d4, d5, d6, d7);  // kt1, k 48..63

    // ---- mid barrier: Vt writes visible; K/V prefetch (vmcnt) NOT drained ----
    asm volatile("s_waitcnt lgkmcnt(0)" ::: "memory");
    __builtin_amdgcn_s_barrier();
    __builtin_amdgcn_sched_barrier(0);

    // ---- O^T += V^T P^T ----
#pragma unroll
    for (int kt = 0; kt < 2; ++kt) {
#pragma unroll
      for (int ss = 0; ss < 2; ++ss) {
        bf16x8 pf = (kt == 0) ? (ss == 0 ? p00 : p01) : (ss == 0 ? p10 : p11);
        int ch = (((kt * 4 + ss * 2 + hi)) ^ (ql & 7)) * 8;
        bf16x8 va0 = *reinterpret_cast<const bf16x8*>(&Vt[ql * 64 + ch]);
        bf16x8 va1 = *reinterpret_cast<const bf16x8*>(&Vt[(32 + ql) * 64 + ch]);
        oA = __builtin_amdgcn_mfma_f32_32x32x16_bf16(va0, pf, oA, 0, 0, 0);
        oB = __builtin_amdgcn_mfma_f32_32x32x16_bf16(va1, pf, oB, 0, 0, 0);
      }
    }
    buf ^= 1;
  }

  // ---- transpose O^T -> O via LDS (reuse Ks as [128 q][64 d], swizzled), store ----
  float linv = 1.0f / l_r;
  __syncthreads();
  unsigned short* Olds = &Ks[0][0];
  int q_l = wid * 32 + ql;
  auto dump = [&](const f32x16& o, int dt) {
#pragma unroll
    for (int g2 = 0; g2 < 4; ++g2) {
      int w0 = cvtpk(o[g2 * 4 + 0] * linv, o[g2 * 4 + 1] * linv);
      int w1 = cvtpk(o[g2 * 4 + 2] * linv, o[g2 * 4 + 3] * linv);
      int dd = dt * 32 + 8 * g2 + 4 * hi;
      int ea = q_l * 64 + (((dd >> 3) ^ (q_l & 7)) << 3) + (dd & 7);
      int2 wv = {w0, w1};
      *reinterpret_cast<int2*>(&Olds[ea]) = wv;
    }
  };
  dump(oA, 0);
  dump(oB, 1);
  __syncthreads();
#pragma unroll
  for (int rep = 0; rep < 4; ++rep) {
    int row = rep * 32 + (tid >> 3);
    int j = tid & 7;
    bf16x8 vv = *reinterpret_cast<const bf16x8*>(&Olds[row * 64 + ((j ^ (row & 7)) << 3)]);
    *reinterpret_cast<bf16x8*>(out + (size_t)(b * L + q0 + row) * 1024 + h * 64 + j * 8) = vv;
  }
}

// ---------------- launch ----------------
extern "C" void kernel_launch(void* const* d_in, const int* in_sizes, int n_in,
                              void* d_out, int out_size, void* d_ws, size_t ws_size,
                              hipStream_t stream) {
  const float* x = (const float*)d_in[0];
  const float* Wq = (const float*)d_in[2];
  const float* bq = (const float*)d_in[3];
  const float* Wk = (const float*)d_in[4];
  const float* bk = (const float*)d_in[5];
  const float* Wv = (const float*)d_in[6];
  const float* bv = (const float*)d_in[7];
  const float* Wo = (const float*)d_in[8];
  const float* bo = (const float*)d_in[9];
  const float* g1 = (const float*)d_in[10];
  const float* b1 = (const float*)d_in[11];
  const float* g2 = (const float*)d_in[12];
  const float* b2 = (const float*)d_in[13];
  const float* W1 = (const float*)d_in[14];
  const float* bf1 = (const float*)d_in[15];
  const float* W2 = (const float*)d_in[16];
  const float* bf2 = (const float*)d_in[17];
  float* out = (float*)d_out;

  const int M = 4096;  // B*L
  char* ws = (char*)d_ws;
  size_t off = 0;
  auto alloc = [&](size_t bytes) -> void* {
    void* p = ws + off;
    off += (bytes + 255) & ~(size_t)255;
    return p;
  };
  unsigned short* WqkvT = (unsigned short*)alloc((size_t)3072 * 1024 * 2);
  unsigned short* WoT = (unsigned short*)alloc((size_t)1024 * 1024 * 2);
  unsigned short* W1T = (unsigned short*)alloc((size_t)4096 * 1024 * 2);
  unsigned short* W2T = (unsigned short*)alloc((size_t)1024 * 4096 * 2);
  float* bqkv = (float*)alloc(3072 * 4);
  unsigned short* actA = (unsigned short*)alloc((size_t)M * 1024 * 2);  // nx / attn_out / nx2
  unsigned short* actB = (unsigned short*)alloc((size_t)M * 4096 * 2);  // qkv / h

  dim3 tb(32, 8);
  transpose_cast4_k<<<dim3(32, 32, 4), tb, 0, stream>>>(Wq, Wk, Wv, Wo, WqkvT, WoT);
  transpose_cast_k<<<dim3(128, 32), tb, 0, stream>>>(W1, W1T, 1024, 4096);
  transpose_cast_k<<<dim3(32, 128), tb, 0, stream>>>(W2, W2T, 4096, 1024);
  concat_bias_k<<<dim3(4), dim3(256), 0, stream>>>(bq, bk, bv, bqkv);

  // nx = LN1(x)
  ln_k<<<dim3(M), dim3(256), 0, stream>>>(x, g1, b1, actA);
  // qkv = nx @ [Wq|Wk|Wv] + b
  gemm_bt_k<0><<<dim3(M / 128, 3072 / 128), dim3(256), 0, stream>>>(actA, WqkvT, bqkv, nullptr, actB, M, 3072, 1024);
  // attn_out
  attn_k<<<dim3(16, 16, 2), dim3(256), 0, stream>>>(actB, actA);
  // x2 = x + attn_out @ Wo + bo   (fp32, into d_out)
  gemm_bt_k<1><<<dim3(M / 128, 1024 / 128), dim3(256), 0, stream>>>(actA, WoT, bo, x, out, M, 1024, 1024);
  // nx2 = LN2(x2)
  ln_k<<<dim3(M), dim3(256), 0, stream>>>(out, g2, b2, actA);
  // h = gelu(nx2 @ W1 + bf1)
  gemm_bt_k<2><<<dim3(M / 128, 4096 / 128), dim3(256), 0, stream>>>(actA, W1T, bf1, nullptr, actB, M, 4096, 1024);
  // out = x2 + h @ W2 + bf2  (in-place residual)
  gemm_bt_k<1><<<dim3(M / 128, 1024 / 128), dim3(256), 0, stream>>>(actB, W2T, bf2, out, out, M, 1024, 4096);
}

// Round 5
// 463.988 us; speedup vs baseline: 3.8646x; 1.0110x over previous
//
#include <hip/hip_runtime.h>
#include <hip/hip_bf16.h>

// ---------------- bf16 bit helpers (bf16 stored as raw ushort bits) ----------------
__device__ __forceinline__ float bfbits2f(unsigned short u) {
  return __uint_as_float(((unsigned int)u) << 16);
}
__device__ __forceinline__ unsigned short f2bfbits(float f) {
  unsigned int x = __float_as_uint(f);
  unsigned int r = (x + 0x7FFFu + ((x >> 16) & 1u)) >> 16;
  return (unsigned short)r;
}

typedef short bf16x8 __attribute__((ext_vector_type(8)));
typedef float f32x4 __attribute__((ext_vector_type(4)));
typedef float f32x16 __attribute__((ext_vector_type(16)));
typedef int i32x4 __attribute__((ext_vector_type(4)));

// v_cvt_pk_bf16_f32: pack two f32 -> u32 of 2 bf16 (RNE)
__device__ __forceinline__ int cvtpk(float lo, float hi_) {
  int r;
  asm("v_cvt_pk_bf16_f32 %0, %1, %2" : "=v"(r) : "v"(lo), "v"(hi_));
  return r;
}
// v_permlane32_swap_b32: a.hi <-> b.lo  (in-place pair swap)
__device__ __forceinline__ void plswap(int& a, int& b) {
  asm("v_permlane32_swap_b32 %0, %1" : "+v"(a), "+v"(b));
}
__device__ __forceinline__ bf16x8 mk8(int a, int b, int c, int d) {
  i32x4 t = {a, b, c, d};
  return __builtin_bit_cast(bf16x8, t);
}

// async global->LDS, 16B per lane; LDS dest must be wave-uniform base (HW adds lane*16)
__device__ __forceinline__ void gload_lds16(const unsigned short* g, unsigned short* l) {
  __builtin_amdgcn_global_load_lds((const __attribute__((address_space(1))) unsigned int*)g,
                                   (__attribute__((address_space(3))) unsigned int*)l, 16, 0, 0);
}

// ---------------- transpose + cast: fp32 [K][N] -> bf16 bits [N][K] ----------------
__global__ __launch_bounds__(256) void transpose_cast_k(const float* __restrict__ in,
                                                        unsigned short* __restrict__ out,
                                                        int K, int N) {
  __shared__ float tile[32][33];
  int n0 = blockIdx.x * 32, k0 = blockIdx.y * 32;
  int tx = threadIdx.x, ty = threadIdx.y;  // (32, 8)
#pragma unroll
  for (int j = 0; j < 32; j += 8)
    tile[ty + j][tx] = in[(size_t)(k0 + ty + j) * N + n0 + tx];
  __syncthreads();
#pragma unroll
  for (int j = 0; j < 32; j += 8)
    out[(size_t)(n0 + ty + j) * K + k0 + tx] = f2bfbits(tile[tx][ty + j]);
}

// four square 1024x1024 transposes in one launch (z = which)
__global__ __launch_bounds__(256) void transpose_cast4_k(const float* __restrict__ w0,
                                                         const float* __restrict__ w1,
                                                         const float* __restrict__ w2,
                                                         const float* __restrict__ w3,
                                                         unsigned short* __restrict__ o012,
                                                         unsigned short* __restrict__ o3) {
  __shared__ float tile[32][33];
  int z = blockIdx.z;
  const float* in = (z == 0) ? w0 : (z == 1) ? w1 : (z == 2) ? w2 : w3;
  unsigned short* out = (z < 3) ? (o012 + (size_t)z * 1024 * 1024) : o3;
  int n0 = blockIdx.x * 32, k0 = blockIdx.y * 32;
  int tx = threadIdx.x, ty = threadIdx.y;
#pragma unroll
  for (int j = 0; j < 32; j += 8)
    tile[ty + j][tx] = in[(size_t)(k0 + ty + j) * 1024 + n0 + tx];
  __syncthreads();
#pragma unroll
  for (int j = 0; j < 32; j += 8)
    out[(size_t)(n0 + ty + j) * 1024 + k0 + tx] = f2bfbits(tile[tx][ty + j]);
}

// ---------------- concat q/k/v biases into [3072] ----------------
__global__ void concat_bias_k(const float* __restrict__ bq, const float* __restrict__ bk,
                              const float* __restrict__ bv, float* __restrict__ out) {
  int i = blockIdx.x * 256 + threadIdx.x;
  if (i < 1024) {
    out[i] = bq[i];
    out[1024 + i] = bk[i];
    out[2048 + i] = bv[i];
  }
}

// ---------------- LayerNorm: fp32 [rows][1024] -> bf16 bits [rows][1024] ----------------
__global__ __launch_bounds__(256) void ln_k(const float* __restrict__ x,
                                            const float* __restrict__ g,
                                            const float* __restrict__ bb,
                                            unsigned short* __restrict__ out) {
  __shared__ float red[8];
  int row = blockIdx.x, tid = threadIdx.x;
  int lane = tid & 63, wv = tid >> 6;
  float4 v = reinterpret_cast<const float4*>(x + (size_t)row * 1024)[tid];
  float s = v.x + v.y + v.z + v.w;
#pragma unroll
  for (int off = 32; off >= 1; off >>= 1) s += __shfl_xor(s, off, 64);
  if (lane == 0) red[wv] = s;
  __syncthreads();
  float mu = (red[0] + red[1] + red[2] + red[3]) * (1.0f / 1024.0f);
  float a0 = v.x - mu, a1 = v.y - mu, a2 = v.z - mu, a3 = v.w - mu;
  float sq = a0 * a0 + a1 * a1 + a2 * a2 + a3 * a3;
#pragma unroll
  for (int off = 32; off >= 1; off >>= 1) sq += __shfl_xor(sq, off, 64);
  if (lane == 0) red[4 + wv] = sq;
  __syncthreads();
  float var = (red[4] + red[5] + red[6] + red[7]) * (1.0f / 1024.0f);
  float rstd = rsqrtf(var + 1e-5f);
  float4 gv = reinterpret_cast<const float4*>(g)[tid];
  float4 bv = reinterpret_cast<const float4*>(bb)[tid];
  ushort4 u;
  u.x = f2bfbits(a0 * rstd * gv.x + bv.x);
  u.y = f2bfbits(a1 * rstd * gv.y + bv.y);
  u.z = f2bfbits(a2 * rstd * gv.z + bv.z);
  u.w = f2bfbits(a3 * rstd * gv.w + bv.w);
  *reinterpret_cast<ushort4*>(out + (size_t)row * 1024 + tid * 4) = u;
}

// ---------------- bf16 MFMA GEMM, double-buffered minimum-2-phase ----------------
// C[M][N] = A[M][K] (bf16) @ BT[N][K]^T (bf16) + bias.
// Per K-step: {vmcnt(0) own-prefetch; s_barrier; STAGE(t+1 -> buf^1); ds_read+MFMA buf}.
// One barrier + one counted drain per tile; prefetch overlaps the whole compute phase.
// MODE 0: out bf16 = acc + bias          (QKV)
// MODE 1: out fp32 = acc + bias + resid  (Wo, W2; in-place resid==out is safe)
// MODE 2: out bf16 = gelu(acc + bias)    (W1)
template <int MODE>
__global__ __launch_bounds__(256) void gemm_bt_k(const unsigned short* __restrict__ A,
                                                 const unsigned short* __restrict__ BT,
                                                 const float* __restrict__ bias,
                                                 const float* __restrict__ resid,
                                                 void* __restrict__ Cout,
                                                 int M, int N, int K) {
  __shared__ unsigned short As[2][128 * 64];
  __shared__ unsigned short Bs[2][128 * 64];
  int tid = threadIdx.x;
  int wid = tid >> 6, lane = tid & 63;
  int m0 = blockIdx.x * 128, n0 = blockIdx.y * 128;
  int wr = wid >> 1, wc = wid & 1;  // 2x2 waves, each 64x64 output
  int cl = lane & 15, g = lane >> 4;

  // staging geometry: chunk index c = i*256+tid; row r=c>>3, col (c&7)*8; lane-linear per wave
  int sr = tid >> 3, sc = (tid & 7) * 8;
  const unsigned short* Abase = &A[(size_t)(m0 + sr) * K + sc];
  const unsigned short* Bbase = &BT[(size_t)(n0 + sr) * K + sc];

  auto stage = [&](int k0s, int bufi) {
#pragma unroll
    for (int i = 0; i < 4; ++i) {
      gload_lds16(Abase + (size_t)i * 32 * K + k0s, &As[bufi][(i * 256 + wid * 64) * 8]);
      gload_lds16(Bbase + (size_t)i * 32 * K + k0s, &Bs[bufi][(i * 256 + wid * 64) * 8]);
    }
  };

  f32x4 acc[4][4];
#pragma unroll
  for (int i = 0; i < 4; i++)
#pragma unroll
    for (int j = 0; j < 4; j++) acc[i][j] = {0.f, 0.f, 0.f, 0.f};

  stage(0, 0);
  int buf = 0;
  for (int k0 = 0; k0 < K; k0 += 64) {
    // own prefetch of buf complete, then align waves (no over-drain: only 8 loads in flight)
    asm volatile("s_waitcnt vmcnt(0)" ::: "memory");
    __builtin_amdgcn_s_barrier();
    __builtin_amdgcn_sched_barrier(0);
    if (k0 + 64 < K) stage(k0 + 64, buf ^ 1);
#pragma unroll
    for (int kk = 0; kk < 64; kk += 32) {
      bf16x8 af[4], bfr[4];
#pragma unroll
      for (int mt = 0; mt < 4; mt++)
        af[mt] = *reinterpret_cast<const bf16x8*>(&As[buf][(wr * 64 + mt * 16 + cl) * 64 + kk + g * 8]);
#pragma unroll
      for (int nt = 0; nt < 4; nt++)
        bfr[nt] = *reinterpret_cast<const bf16x8*>(&Bs[buf][(wc * 64 + nt * 16 + cl) * 64 + kk + g * 8]);
#pragma unroll
      for (int mt = 0; mt < 4; mt++)
#pragma unroll
        for (int nt = 0; nt < 4; nt++)
          acc[mt][nt] = __builtin_amdgcn_mfma_f32_16x16x32_bf16(af[mt], bfr[nt], acc[mt][nt], 0, 0, 0);
    }
    buf ^= 1;
  }

  // epilogue: D[row=(lane>>4)*4+r][col=lane&15] per 16x16 frag
#pragma unroll
  for (int mt = 0; mt < 4; mt++) {
#pragma unroll
    for (int nt = 0; nt < 4; nt++) {
#pragma unroll
      for (int r = 0; r < 4; r++) {
        int gr = m0 + wr * 64 + mt * 16 + g * 4 + r;
        int gc = n0 + wc * 64 + nt * 16 + cl;
        float v = acc[mt][nt][r] + bias[gc];
        if constexpr (MODE == 1) {
          v += resid[(size_t)gr * N + gc];
          ((float*)Cout)[(size_t)gr * N + gc] = v;
        } else if constexpr (MODE == 2) {
          v = 0.5f * v * (1.0f + erff(v * 0.70710678118654752f));
          ((unsigned short*)Cout)[(size_t)gr * N + gc] = f2bfbits(v);
        } else {
          ((unsigned short*)Cout)[(size_t)gr * N + gc] = f2bfbits(v);
        }
      }
    }
  }
}

// ---------------- MFMA flash attention v4: swapped-operand 32x32, in-register softmax ----------------
// qkv bf16 [B*L][3072] (q|k|v, col=h*64+d) -> out bf16 [B*L][1024].
// Block: 256 thr = 4 waves; QBLK=128 (wave owns 32 q rows, q = lane&31). KV tiles of 64.
// S^T = mfma_32x32x16(K, Q): lane holds a q-row's 32 scores -> in-lane softmax,
// P packed via cvt_pk_bf16 + permlane32_swap (no LDS for P). O^T = mfma(V^T, P^T).
// K: global_load_lds double-buffered (pre-swizzled source); V: reg-prefetched, b32 scatter.
__global__ __launch_bounds__(256) void attn_k(const unsigned short* __restrict__ qkv,
                                              unsigned short* __restrict__ out) {
  __shared__ unsigned short Ks[2][64 * 64];  // [k-row][d], 16B-chunk c stored at c^(row&7)
  __shared__ unsigned short Vt[64 * 64];     // [d-row][k], same swizzle

  const int L = 2048, RS = 3072;
  const float SCALE = 0.125f * 1.44269504f;  // 1/sqrt(64) * log2(e)
  int tid = threadIdx.x;
  int wid = tid >> 6, lane = tid & 63;
  int qt = (int)gridDim.x - 1 - (int)blockIdx.x;  // heavy tiles dispatch first
  int h = blockIdx.y, b = blockIdx.z;
  int q0 = qt * 128;
  int qw = q0 + wid * 32;
  int ql = lane & 31;
  int hi = lane >> 5;
  int qg = qw + ql;

  const unsigned short* kbase = qkv + (size_t)(b * L) * RS + 1024 + h * 64;
  const unsigned short* vbase = kbase + 1024;

  // ---- Q fragments (B-frag: col=q=lane&31, k=d=hi*8+e), pre-scaled by SCALE ----
  bf16x8 qf[4];
  {
    const unsigned short* qp = qkv + (size_t)(b * L + qg) * RS + h * 64 + hi * 8;
#pragma unroll
    for (int s = 0; s < 4; ++s) {
      bf16x8 qr = *reinterpret_cast<const bf16x8*>(qp + s * 16);
      int w0 = cvtpk(bfbits2f((unsigned short)qr[0]) * SCALE, bfbits2f((unsigned short)qr[1]) * SCALE);
      int w1 = cvtpk(bfbits2f((unsigned short)qr[2]) * SCALE, bfbits2f((unsigned short)qr[3]) * SCALE);
      int w2 = cvtpk(bfbits2f((unsigned short)qr[4]) * SCALE, bfbits2f((unsigned short)qr[5]) * SCALE);
      int w3 = cvtpk(bfbits2f((unsigned short)qr[6]) * SCALE, bfbits2f((unsigned short)qr[7]) * SCALE);
      qf[s] = mk8(w0, w1, w2, w3);
    }
  }

  // ---- K staging: thread covers swizzled chunks tid and tid+256 ----
  int kr0 = tid >> 3, kc0 = tid & 7;
  size_t koff0 = (size_t)kr0 * RS + ((kc0 ^ (kr0 & 7)) * 8);  // +32*RS for second half
  // ---- V staging: thread loads rows vkp,vkp+1 (8 d each), writes 8 packed b32 ----
  int vkp = (tid & 31) * 2, vd0 = (tid >> 5) * 8;
  int vwaddr[8];
#pragma unroll
  for (int j = 0; j < 8; ++j) {
    int d = vd0 + j;
    vwaddr[j] = d * 64 + (((vkp >> 3) ^ (d & 7)) << 3) + (vkp & 7);
  }

  float m_r = -3.0e38f, l_r = 0.f;
  f32x16 oA, oB;
#pragma unroll
  for (int r = 0; r < 16; ++r) { oA[r] = 0.f; oB[r] = 0.f; }

  int nt = 2 * qt + 2;

  // prologue: issue tile 0
  gload_lds16(kbase + koff0, &Ks[0][(wid * 64) * 8]);
  gload_lds16(kbase + koff0 + (size_t)32 * RS, &Ks[0][(256 + wid * 64) * 8]);
  bf16x8 vr0, vr1;
  {
    const unsigned short* vp = vbase + (size_t)vkp * RS + vd0;
    vr0 = *reinterpret_cast<const bf16x8*>(vp);
    vr1 = *reinterpret_cast<const bf16x8*>(vp + RS);
  }

  int buf = 0;
  for (int tt = 0; tt < nt; ++tt) {
    int kb = tt * 64;
    // ---- tile-top: my K(t)/V(t) loads done; align waves ----
    asm volatile("s_waitcnt vmcnt(0)" ::: "memory");
    __builtin_amdgcn_s_barrier();
    __builtin_amdgcn_sched_barrier(0);

    // ---- scatter V(t) regs -> Vt (transposed, swizzled, b32-packed) ----
#pragma unroll
    for (int j = 0; j < 8; ++j) {
      unsigned int pk = (unsigned int)(unsigned short)vr0[j] |
                        ((unsigned int)(unsigned short)vr1[j] << 16);
      *reinterpret_cast<unsigned int*>(&Vt[vwaddr[j]]) = pk;
    }

    // ---- prefetch tile t+1 (stays in flight across the mid barrier) ----
    if (tt + 1 < nt) {
      size_t kb1r = (size_t)(tt + 1) * 64 * RS;
      gload_lds16(kbase + kb1r + koff0, &Ks[buf ^ 1][(wid * 64) * 8]);
      gload_lds16(kbase + kb1r + koff0 + (size_t)32 * RS, &Ks[buf ^ 1][(256 + wid * 64) * 8]);
      const unsigned short* vp = vbase + kb1r + (size_t)vkp * RS + vd0;
      vr0 = *reinterpret_cast<const bf16x8*>(vp);
      vr1 = *reinterpret_cast<const bf16x8*>(vp + RS);
    }

    // ---- S^T = mfma(K, Q): rows k = lane&31 (+32), cols q ----
    f32x16 s0, s1;
#pragma unroll
    for (int r = 0; r < 16; ++r) { s0[r] = 0.f; s1[r] = 0.f; }
#pragma unroll
    for (int s = 0; s < 4; ++s) {
      int ch = ((s * 2 + hi) ^ (ql & 7)) * 8;
      bf16x8 ka0 = *reinterpret_cast<const bf16x8*>(&Ks[buf][ql * 64 + ch]);
      bf16x8 ka1 = *reinterpret_cast<const bf16x8*>(&Ks[buf][(32 + ql) * 64 + ch]);
      s0 = __builtin_amdgcn_mfma_f32_32x32x16_bf16(ka0, qf[s], s0, 0, 0, 0);
      s1 = __builtin_amdgcn_mfma_f32_32x32x16_bf16(ka1, qf[s], s1, 0, 0, 0);
    }

    // ---- causal mask (k = kb + (r&3)+8*(r>>2)+4*hi [+32]) ----
    if (kb + 63 > qw) {
#pragma unroll
      for (int r = 0; r < 16; ++r) {
        int ko = kb + (r & 3) + 8 * (r >> 2) + 4 * hi;
        if (ko > qg) s0[r] = -3.0e38f;
        if (ko + 32 > qg) s1[r] = -3.0e38f;
      }
    }

    // ---- in-register online softmax (exp2 domain) ----
#define MX4(v, i) fmaxf(fmaxf(v[i], v[i + 1]), fmaxf(v[i + 2], v[i + 3]))
    float ma = fmaxf(fmaxf(MX4(s0, 0), MX4(s0, 4)), fmaxf(MX4(s0, 8), MX4(s0, 12)));
    float mb = fmaxf(fmaxf(MX4(s1, 0), MX4(s1, 4)), fmaxf(MX4(s1, 8), MX4(s1, 12)));
    float mx = fmaxf(ma, mb);
    mx = fmaxf(mx, __shfl_xor(mx, 32, 64));
    float mnew = fmaxf(m_r, mx);
    float corr = exp2f(m_r - mnew);
    m_r = mnew;
#pragma unroll
    for (int r = 0; r < 16; ++r) {
      s0[r] = exp2f(s0[r] - mnew);
      s1[r] = exp2f(s1[r] - mnew);
    }
#define SM4(v, i) ((v[i] + v[i + 1]) + (v[i + 2] + v[i + 3]))
    float rs = ((SM4(s0, 0) + SM4(s0, 4)) + (SM4(s0, 8) + SM4(s0, 12))) +
               ((SM4(s1, 0) + SM4(s1, 4)) + (SM4(s1, 8) + SM4(s1, 12)));
    rs += __shfl_xor(rs, 32, 64);
    l_r = l_r * corr + rs;
#pragma unroll
    for (int r = 0; r < 16; ++r) { oA[r] *= corr; oB[r] *= corr; }

    // ---- pack P -> bf16 frags in-register (cvt_pk + permlane32_swap) ----
    int c0 = cvtpk(s0[0], s0[1]), c1 = cvtpk(s0[2], s0[3]);
    int c2 = cvtpk(s0[4], s0[5]), c3 = cvtpk(s0[6], s0[7]);
    int c4 = cvtpk(s0[8], s0[9]), c5 = cvtpk(s0[10], s0[11]);
    int c6 = cvtpk(s0[12], s0[13]), c7 = cvtpk(s0[14], s0[15]);
    plswap(c0, c2); plswap(c1, c3); plswap(c4, c6); plswap(c5, c7);
    bf16x8 p00 = mk8(c0, c1, c2, c3);  // kt0, k 0..15
    bf16x8 p01 = mk8(c4, c5, c6, c7);  // kt0, k 16..31
    int d0 = cvtpk(s1[0], s1[1]), d1 = cvtpk(s1[2], s1[3]);
    int d2 = cvtpk(s1[4], s1[5]), d3 = cvtpk(s1[6], s1[7]);
    int d4 = cvtpk(s1[8], s1[9]), d5 = cvtpk(s1[10], s1[11]);
    int d6 = cvtpk(s1[12], s1[13]), d7 = cvtpk(s1[14], s1[15]);
    plswap(d0, d2); plswap(d1, d3); plswap(d4, d6); plswap(d5, d7);
    bf16x8 p10 = mk8(d0, d1, d2, d3);  // kt1, k 32..47
    bf16x8 p11 = mk8(d4, d5, d6, d7);  // kt1, k 48..63

    // ---- mid barrier: Vt writes visible; K/V prefetch (vmcnt) NOT drained ----
    asm volatile("s_waitcnt lgkmcnt(0)" ::: "memory");
    __builtin_amdgcn_s_barrier();
    __builtin_amdgcn_sched_barrier(0);

    // ---- O^T += V^T P^T ----
#pragma unroll
    for (int kt = 0; kt < 2; ++kt) {
#pragma unroll
      for (int ss = 0; ss < 2; ++ss) {
        bf16x8 pf = (kt == 0) ? (ss == 0 ? p00 : p01) : (ss == 0 ? p10 : p11);
        int ch = (((kt * 4 + ss * 2 + hi)) ^ (ql & 7)) * 8;
        bf16x8 va0 = *reinterpret_cast<const bf16x8*>(&Vt[ql * 64 + ch]);
        bf16x8 va1 = *reinterpret_cast<const bf16x8*>(&Vt[(32 + ql) * 64 + ch]);
        oA = __builtin_amdgcn_mfma_f32_32x32x16_bf16(va0, pf, oA, 0, 0, 0);
        oB = __builtin_amdgcn_mfma_f32_32x32x16_bf16(va1, pf, oB, 0, 0, 0);
      }
    }
    buf ^= 1;
  }

  // ---- transpose O^T -> O via LDS (reuse Ks as [128 q][64 d], swizzled), store ----
  float linv = 1.0f / l_r;
  __syncthreads();
  unsigned short* Olds = &Ks[0][0];
  int q_l = wid * 32 + ql;
  auto dump = [&](const f32x16& o, int dt) {
#pragma unroll
    for (int g2 = 0; g2 < 4; ++g2) {
      int w0 = cvtpk(o[g2 * 4 + 0] * linv, o[g2 * 4 + 1] * linv);
      int w1 = cvtpk(o[g2 * 4 + 2] * linv, o[g2 * 4 + 3] * linv);
      int dd = dt * 32 + 8 * g2 + 4 * hi;
      int ea = q_l * 64 + (((dd >> 3) ^ (q_l & 7)) << 3) + (dd & 7);
      int2 wv = {w0, w1};
      *reinterpret_cast<int2*>(&Olds[ea]) = wv;
    }
  };
  dump(oA, 0);
  dump(oB, 1);
  __syncthreads();
#pragma unroll
  for (int rep = 0; rep < 4; ++rep) {
    int row = rep * 32 + (tid >> 3);
    int j = tid & 7;
    bf16x8 vv = *reinterpret_cast<const bf16x8*>(&Olds[row * 64 + ((j ^ (row & 7)) << 3)]);
    *reinterpret_cast<bf16x8*>(out + (size_t)(b * L + q0 + row) * 1024 + h * 64 + j * 8) = vv;
  }
}

// ---------------- launch ----------------
extern "C" void kernel_launch(void* const* d_in, const int* in_sizes, int n_in,
                              void* d_out, int out_size, void* d_ws, size_t ws_size,
                              hipStream_t stream) {
  const float* x = (const float*)d_in[0];
  const float* Wq = (const float*)d_in[2];
  const float* bq = (const float*)d_in[3];
  const float* Wk = (const float*)d_in[4];
  const float* bk = (const float*)d_in[5];
  const float* Wv = (const float*)d_in[6];
  const float* bv = (const float*)d_in[7];
  const float* Wo = (const float*)d_in[8];
  const float* bo = (const float*)d_in[9];
  const float* g1 = (const float*)d_in[10];
  const float* b1 = (const float*)d_in[11];
  const float* g2 = (const float*)d_in[12];
  const float* b2 = (const float*)d_in[13];
  const float* W1 = (const float*)d_in[14];
  const float* bf1 = (const float*)d_in[15];
  const float* W2 = (const float*)d_in[16];
  const float* bf2 = (const float*)d_in[17];
  float* out = (float*)d_out;

  const int M = 4096;  // B*L
  char* ws = (char*)d_ws;
  size_t off = 0;
  auto alloc = [&](size_t bytes) -> void* {
    void* p = ws + off;
    off += (bytes + 255) & ~(size_t)255;
    return p;
  };
  unsigned short* WqkvT = (unsigned short*)alloc((size_t)3072 * 1024 * 2);
  unsigned short* WoT = (unsigned short*)alloc((size_t)1024 * 1024 * 2);
  unsigned short* W1T = (unsigned short*)alloc((size_t)4096 * 1024 * 2);
  unsigned short* W2T = (unsigned short*)alloc((size_t)1024 * 4096 * 2);
  float* bqkv = (float*)alloc(3072 * 4);
  unsigned short* actA = (unsigned short*)alloc((size_t)M * 1024 * 2);  // nx / attn_out / nx2
  unsigned short* actB = (unsigned short*)alloc((size_t)M * 4096 * 2);  // qkv / h

  dim3 tb(32, 8);
  transpose_cast4_k<<<dim3(32, 32, 4), tb, 0, stream>>>(Wq, Wk, Wv, Wo, WqkvT, WoT);
  transpose_cast_k<<<dim3(128, 32), tb, 0, stream>>>(W1, W1T, 1024, 4096);
  transpose_cast_k<<<dim3(32, 128), tb, 0, stream>>>(W2, W2T, 4096, 1024);
  concat_bias_k<<<dim3(4), dim3(256), 0, stream>>>(bq, bk, bv, bqkv);

  // nx = LN1(x)
  ln_k<<<dim3(M), dim3(256), 0, stream>>>(x, g1, b1, actA);
  // qkv = nx @ [Wq|Wk|Wv] + b
  gemm_bt_k<0><<<dim3(M / 128, 3072 / 128), dim3(256), 0, stream>>>(actA, WqkvT, bqkv, nullptr, actB, M, 3072, 1024);
  // attn_out
  attn_k<<<dim3(16, 16, 2), dim3(256), 0, stream>>>(actB, actA);
  // x2 = x + attn_out @ Wo + bo   (fp32, into d_out)
  gemm_bt_k<1><<<dim3(M / 128, 1024 / 128), dim3(256), 0, stream>>>(actA, WoT, bo, x, out, M, 1024, 1024);
  // nx2 = LN2(x2)
  ln_k<<<dim3(M), dim3(256), 0, stream>>>(out, g2, b2, actA);
  // h = gelu(nx2 @ W1 + bf1)
  gemm_bt_k<2><<<dim3(M / 128, 4096 / 128), dim3(256), 0, stream>>>(actA, W1T, bf1, nullptr, actB, M, 4096, 1024);
  // out = x2 + h @ W2 + bf2  (in-place residual)
  gemm_bt_k<1><<<dim3(M / 128, 1024 / 128), dim3(256), 0, stream>>>(actB, W2T, bf2, out, out, M, 1024, 4096);
}